// Round 15
// baseline (530.365 us; speedup 1.0000x reference)
//
#include <hip/hip_runtime.h>

#define D 128
#define EDIM 64
#define NODE_F 32
#define EDGE_F 16
#define B_PAIRS 256
#define MAXN 64
#define PROP_STEPS 3

typedef __attribute__((ext_vector_type(4))) short short4v;
typedef __attribute__((ext_vector_type(8))) short short8;
typedef __attribute__((ext_vector_type(16))) float floatx16;

__device__ __forceinline__ short f2bf(float x) {
  unsigned u = __float_as_uint(x);
  u = (u + 0x7fff + ((u >> 16) & 1)) >> 16;   // RNE
  return (short)u;
}

__device__ __forceinline__ float bf2f(short s) {
  return __uint_as_float(((unsigned)(unsigned short)s) << 16);
}

// ---------------- CSR build + inv init ----------------
__global__ __launch_bounds__(256) void hist_kernel(const int* __restrict__ to_idx,
                                                   int* __restrict__ deg,
                                                   int* __restrict__ inv, int E)
{
  int g = gridDim.x * 256;
  for (int e = blockIdx.x * 256 + threadIdx.x; e < E; e += g)
    atomicAdd(&deg[to_idx[e]], 1);
  for (int i = blockIdx.x * 256 + threadIdx.x; i < 2 * B_PAIRS * MAXN; i += g)
    inv[i] = -1;
}

__global__ __launch_bounds__(1024) void scan_kernel(const int* __restrict__ deg,
                                                    int* __restrict__ offsets,
                                                    int* __restrict__ cursor,
                                                    const int* __restrict__ pos,
                                                    int* __restrict__ inv, int N)
{
  __shared__ int part[1024];
  int t = threadIdx.x;
  int chunk = (N + 1023) / 1024;
  int s0 = t * chunk, s1 = min(s0 + chunk, N);
  int sum = 0;
  for (int i = s0; i < s1; i++) sum += deg[i];
  part[t] = sum;
  __syncthreads();
  for (int off = 1; off < 1024; off <<= 1) {
    int v = 0;
    if (t >= off) v = part[t - off];
    __syncthreads();
    if (t >= off) part[t] += v;
    __syncthreads();
  }
  int base = (t == 0) ? 0 : part[t - 1];
  for (int i = s0; i < s1; i++) {
    offsets[i] = base; cursor[i] = base;
    base += deg[i];
  }
  if (t == 1023) offsets[N] = part[1023];
  for (int i = t; i < N; i += 1024) inv[pos[i]] = i;
}

__global__ __launch_bounds__(256) void scatter_csr(const int* __restrict__ to_idx,
                                                   int* __restrict__ cursor,
                                                   int* __restrict__ elist, int E)
{
  for (int e = blockIdx.x * 256 + threadIdx.x; e < E; e += gridDim.x * 256) {
    int pos = atomicAdd(&cursor[to_idx[e]], 1);
    elist[pos] = e;
  }
}

// ---------------- weight prep: fragment-order layouts ----------------
__global__ __launch_bounds__(256) void prep_w(
    const float* __restrict__ W_node, const float* __restrict__ W_edge,
    const float* __restrict__ W1, const float* __restrict__ W2,
    const float* __restrict__ Wu,
    const float* __restrict__ Wa1, const float* __restrict__ Wa2,
    short* __restrict__ Wfn, short* __restrict__ Wfe,
    short* __restrict__ Wf1a, short* __restrict__ Wf1b, short* __restrict__ Wf1e,
    short* __restrict__ Wf2, short* __restrict__ Wfu,
    short* __restrict__ Wfa1, short* __restrict__ Wfa2)
{
  int idx = blockIdx.x * 256 + threadIdx.x;
  if (idx < 4096) {
    int step = idx >> 11, hi = (idx >> 10) & 1;
    int n = (idx >> 3) & 127, j = idx & 7;
    int k = step * 16 + hi * 8 + j;
    Wfn[idx] = f2bf(W_node[(size_t)k * 128 + n]);
  } else if (idx < 5120) {
    int i = idx - 4096;
    int hi = (i >> 9) & 1, n = (i >> 3) & 63, j = i & 7;
    int k = hi * 8 + j;
    Wfe[i] = f2bf(W_edge[(size_t)k * 64 + n]);
  } else if (idx < 37888) {
    int i = idx - 5120;
    int step = i >> 12, hi = (i >> 11) & 1;
    int n = (i >> 3) & 255, j = i & 7;
    int k = step * 16 + hi * 8 + j;
    Wf1a[i] = f2bf(W1[(size_t)k * 256 + n]);
  } else if (idx < 70656) {
    int i = idx - 37888;
    int step = i >> 12, hi = (i >> 11) & 1;
    int n = (i >> 3) & 255, j = i & 7;
    int k = step * 16 + hi * 8 + j;
    Wf1b[i] = f2bf(W1[(size_t)(128 + k) * 256 + n]);
  } else if (idx < 87040) {
    int i = idx - 70656;
    int step = i >> 12, hi = (i >> 11) & 1;
    int n = (i >> 3) & 255, j = i & 7;
    int k = step * 16 + hi * 8 + j;
    Wf1e[i] = f2bf(W1[(size_t)(256 + k) * 256 + n]);
  } else if (idx < 152576) {
    int i = idx - 87040;
    int step = i >> 12, hi = (i >> 11) & 1;
    int n = (i >> 3) & 255, j = i & 7;
    int k = step * 16 + hi * 8 + j;
    Wf2[i] = f2bf(W2[(size_t)k * 256 + n]);
  } else if (idx < 201728) {
    int i = idx - 152576;
    int step = i >> 11, hi = (i >> 10) & 1;
    int n = (i >> 3) & 127, j = i & 7;
    int k = step * 16 + hi * 8 + j;
    Wfu[i] = f2bf(Wu[(size_t)k * 128 + n]);
  } else if (idx < 218112) {
    int i = idx - 201728;
    int step = i >> 11, hi = (i >> 10) & 1;
    int n = (i >> 3) & 127, j = i & 7;
    int k = step * 16 + hi * 8 + j;
    Wfa1[i] = f2bf(Wa1[(size_t)k * 128 + n]);
  } else if (idx < 234496) {
    int i = idx - 218112;
    int step = i >> 11, hi = (i >> 10) & 1;
    int n = (i >> 3) & 127, j = i & 7;
    int k = step * 16 + hi * 8 + j;
    Wfa2[i] = f2bf(Wa2[(size_t)k * 128 + n]);
  }
}

// ---------------- node encoder + fused P1/P2 ----------------
__global__ __launch_bounds__(256, 3) void enc_nodes_p(
    const float* __restrict__ nf, const short* __restrict__ Wfn,
    const float* __restrict__ b_node, float* __restrict__ h,
    short* __restrict__ hb,
    const short* __restrict__ Wf1a, const short* __restrict__ Wf1b,
    short* __restrict__ P1f, short* __restrict__ P2f, int N)
{
  __shared__ short sN[32 * 40];
  __shared__ short sH[32 * 136];
  int t = threadIdx.x;
  int ln = t & 63, w = t >> 6;
  int l31 = ln & 31, hi = ln >> 5;
  int n0 = blockIdx.x * 32;

  {
    int r = t >> 3, q = t & 7;
    float4 v = {0.f, 0.f, 0.f, 0.f};
    if (n0 + r < N) v = *(const float4*)(nf + (size_t)(n0 + r) * 32 + q * 4);
    short4v s;
    s[0] = f2bf(v.x); s[1] = f2bf(v.y); s[2] = f2bf(v.z); s[3] = f2bf(v.w);
    *(short4v*)(sN + r * 40 + q * 4) = s;
  }
  __syncthreads();

  int col = w * 32 + l31;
  {
    floatx16 acc;
    #pragma unroll
    for (int i = 0; i < 16; i++) acc[i] = 0.f;
    #pragma unroll
    for (int step = 0; step < 2; step++) {
      short8 a = *(const short8*)(sN + l31 * 40 + step * 16 + hi * 8);
      short8 b = *(const short8*)(Wfn + (size_t)(step * 2 + hi) * 1024 + col * 8);
      acc = __builtin_amdgcn_mfma_f32_32x32x16_bf16(a, b, acc, 0, 0, 0);
    }
    float bv = b_node[col];
    #pragma unroll
    for (int reg = 0; reg < 16; reg++) {
      int row = (reg & 3) + 8 * (reg >> 2) + 4 * hi;
      int n = n0 + row;
      float v = acc[reg] + bv;
      short bf = f2bf(v);
      if (n < N) {
        h[(size_t)n * 128 + col] = v;
        hb[(size_t)n * 128 + col] = bf;
      }
      sH[row * 136 + col] = bf;
    }
  }
  __syncthreads();

  int cb = w * 64;
  const int arow = l31 * 136;
  const int bc0 = (cb + l31) * 8, bc1 = (cb + 32 + l31) * 8;
  floatx16 acc[2][2];
  #pragma unroll
  for (int o = 0; o < 2; o++)
    #pragma unroll
    for (int ct = 0; ct < 2; ct++)
      #pragma unroll
      for (int i = 0; i < 16; i++) acc[o][ct][i] = 0.f;

  #pragma unroll
  for (int step = 0; step < 8; step++) {
    short8 a = *(const short8*)(sH + arow + step * 16 + hi * 8);
    short8 ba0 = *(const short8*)(Wf1a + (size_t)(step * 2 + hi) * 2048 + bc0);
    short8 ba1 = *(const short8*)(Wf1a + (size_t)(step * 2 + hi) * 2048 + bc1);
    short8 bb0 = *(const short8*)(Wf1b + (size_t)(step * 2 + hi) * 2048 + bc0);
    short8 bb1 = *(const short8*)(Wf1b + (size_t)(step * 2 + hi) * 2048 + bc1);
    acc[0][0] = __builtin_amdgcn_mfma_f32_32x32x16_bf16(a, ba0, acc[0][0], 0, 0, 0);
    acc[0][1] = __builtin_amdgcn_mfma_f32_32x32x16_bf16(a, ba1, acc[0][1], 0, 0, 0);
    acc[1][0] = __builtin_amdgcn_mfma_f32_32x32x16_bf16(a, bb0, acc[1][0], 0, 0, 0);
    acc[1][1] = __builtin_amdgcn_mfma_f32_32x32x16_bf16(a, bb1, acc[1][1], 0, 0, 0);
  }

  #pragma unroll
  for (int ct = 0; ct < 2; ct++) {
    int pcol = cb + ct * 32 + l31;
    #pragma unroll
    for (int reg = 0; reg < 16; reg++) {
      int row = (reg & 3) + 8 * (reg >> 2) + 4 * hi;
      int n = n0 + row;
      if (n < N) {
        P1f[(size_t)n * 256 + pcol] = f2bf(acc[0][ct][reg]);
        P2f[(size_t)n * 256 + pcol] = f2bf(acc[1][ct][reg]);
      }
    }
  }
}

// ---------------- edge encoder -> fragment-major CSR storage ----------------
// ebF layout per 64-edge block: [kslot(8)][row(64)][8shorts] = 4096 shorts.
// A-fragment load in msg: lanes l31 read consecutive 16B -> fully coalesced.
__global__ __launch_bounds__(256, 4) void enc_edges_f(
    const float* __restrict__ ef, const int* __restrict__ elist,
    const short* __restrict__ Wfe, const float* __restrict__ b_edge,
    short* __restrict__ ebF, int E)
{
  __shared__ short sE[64 * 24];
  __shared__ short sF[64 * 72];
  __shared__ int eid_s[64];

  int t = threadIdx.x;
  int ln = t & 63, w = t >> 6;
  int l31 = ln & 31, hi = ln >> 5;
  int e0 = blockIdx.x * 64;

  if (t < 64) eid_s[t] = (e0 + t < E) ? elist[e0 + t] : 0;
  __syncthreads();

  {
    int r = t >> 2, q = t & 3;
    float4 v = *(const float4*)(ef + (size_t)eid_s[r] * 16 + q * 4);
    short4v s;
    s[0] = f2bf(v.x); s[1] = f2bf(v.y); s[2] = f2bf(v.z); s[3] = f2bf(v.w);
    *(short4v*)(sE + r * 24 + q * 4) = s;
  }
  __syncthreads();

  {
    int rowb = (w & 1) * 32, cbq = (w >> 1) * 32;
    floatx16 acc;
    #pragma unroll
    for (int i = 0; i < 16; i++) acc[i] = 0.f;
    short8 a = *(const short8*)(sE + (rowb + l31) * 24 + hi * 8);
    short8 b = *(const short8*)(Wfe + (size_t)hi * 512 + (cbq + l31) * 8);
    acc = __builtin_amdgcn_mfma_f32_32x32x16_bf16(a, b, acc, 0, 0, 0);
    int col = cbq + l31;
    float bv = b_edge[col];
    #pragma unroll
    for (int reg = 0; reg < 16; reg++) {
      int row = rowb + (reg & 3) + 8 * (reg >> 2) + 4 * hi;
      sF[row * 72 + col] = f2bf(acc[reg] + bv);
    }
  }
  __syncthreads();

  // fragment-major store: i = [kslot][row][j]
  for (int i = t; i < 4096; i += 256) {
    int kslot = i >> 9, row = (i >> 3) & 63, j = i & 7;
    ebF[(size_t)blockIdx.x * 4096 + i] = sF[row * 72 + kslot * 8 + j];
  }
}

// ---------------- message: S-staging + coalesced Pe recompute + GEMM2 + fused CSR agg ----------------
__global__ __launch_bounds__(256, 4) void msg_mfma(
    const short* __restrict__ P1f, const short* __restrict__ P2f,
    const short* __restrict__ ebF,
    const int* __restrict__ from_idx, const int* __restrict__ to_idx,
    const int* __restrict__ elist, const int* __restrict__ offsets,
    const short* __restrict__ Wf1e, const float* __restrict__ b1,
    const short* __restrict__ Wf2, const float* __restrict__ b2,
    float* __restrict__ agg, int E)
{
  __shared__ short sA[64 * 264];
  __shared__ int from_s[64], to_s[64];
  __shared__ int rend_s[64], inter_s[64];

  int t = threadIdx.x;
  int ln = t & 63, w = t >> 6;
  int l31 = ln & 31, hi = ln >> 5;
  int cb = w * 64;
  int e0 = blockIdx.x * 64;

  if (t < 64) {
    int idx = e0 + t;
    int eid = (idx < E) ? elist[idx] : 0;
    from_s[t] = from_idx[eid];
    to_s[t] = (idx < E) ? to_idx[eid] : -1;
  }
  __syncthreads();

  if (t < 64) {
    int nd = to_s[t];
    bool head = (t == 0) || (nd != to_s[t - 1]);
    if (head && nd >= 0) {
      int re = t + 1;
      while (re < 64 && to_s[re] == nd) re++;
      rend_s[t] = re;
      inter_s[t] = (offsets[nd] == e0 + t) && (offsets[nd + 1] == e0 + re) ? 1 : 0;
    }
  }

  // ---- Pe recompute: pe = e @ W1e (K=64); A coalesced from fragment-major ebF
  floatx16 pe[2][2];
  #pragma unroll
  for (int rg = 0; rg < 2; rg++)
    #pragma unroll
    for (int ct = 0; ct < 2; ct++)
      #pragma unroll
      for (int i = 0; i < 16; i++) pe[rg][ct][i] = 0.f;

  {
    const short* ebase = ebF + (size_t)blockIdx.x * 4096;
    const int bc0 = (cb + l31) * 8, bc1 = (cb + 32 + l31) * 8;
    #pragma unroll
    for (int step = 0; step < 4; step++) {
      const short* kslotp = ebase + (size_t)(step * 2 + hi) * 512;
      short8 a0 = *(const short8*)(kslotp + l31 * 8);
      short8 a1 = *(const short8*)(kslotp + (32 + l31) * 8);
      short8 b0 = *(const short8*)(Wf1e + (size_t)(step * 2 + hi) * 2048 + bc0);
      short8 b1v = *(const short8*)(Wf1e + (size_t)(step * 2 + hi) * 2048 + bc1);
      pe[0][0] = __builtin_amdgcn_mfma_f32_32x32x16_bf16(a0, b0,  pe[0][0], 0, 0, 0);
      pe[0][1] = __builtin_amdgcn_mfma_f32_32x32x16_bf16(a0, b1v, pe[0][1], 0, 0, 0);
      pe[1][0] = __builtin_amdgcn_mfma_f32_32x32x16_bf16(a1, b0,  pe[1][0], 0, 0, 0);
      pe[1][1] = __builtin_amdgcn_mfma_f32_32x32x16_bf16(a1, b1v, pe[1][1], 0, 0, 0);
    }
  }

  // stage S = P1[from] + P2[to] (bf16) into sA
  for (int i = t; i < 2048; i += 256) {
    int r = i >> 5, c8 = (i & 31) * 8;
    int nd = to_s[r]; if (nd < 0) nd = 0;
    short8 a = *(const short8*)(P1f + (size_t)from_s[r] * 256 + c8);
    short8 b = *(const short8*)(P2f + (size_t)nd * 256 + c8);
    short8 o;
    #pragma unroll
    for (int j = 0; j < 8; j++)
      o[j] = f2bf(bf2f(a[j]) + bf2f(b[j]));
    *(short8*)(sA + r * 264 + c8) = o;
  }
  __syncthreads();

  // combine: hidden = relu(S + pe + b1) at wave-owned C-layout positions
  #pragma unroll
  for (int rg = 0; rg < 2; rg++)
    #pragma unroll
    for (int ct = 0; ct < 2; ct++) {
      int col = cb + ct * 32 + l31;
      float bv = b1[col];
      #pragma unroll
      for (int reg = 0; reg < 16; reg++) {
        int row = rg * 32 + (reg & 3) + 8 * (reg >> 2) + 4 * hi;
        float s = bf2f(sA[row * 264 + col]);
        sA[row * 264 + col] = f2bf(fmaxf(s + pe[rg][ct][reg] + bv, 0.f));
      }
    }
  __syncthreads();

  const int arow0 = l31 * 264;
  const int arow1 = (32 + l31) * 264;
  const int bc0 = (cb + l31) * 8;
  const int bc1 = (cb + 32 + l31) * 8;

  floatx16 acc2[2][2];
  #pragma unroll
  for (int rg = 0; rg < 2; rg++)
    #pragma unroll
    for (int ct = 0; ct < 2; ct++)
      #pragma unroll
      for (int i = 0; i < 16; i++) acc2[rg][ct][i] = 0.f;

  {
    short8 b2buf[3][2];
    #pragma unroll
    for (int s = 0; s < 3; s++) {
      const short* bb = Wf2 + (size_t)(s * 2 + hi) * 2048;
      b2buf[s][0] = *(const short8*)(bb + bc0);
      b2buf[s][1] = *(const short8*)(bb + bc1);
    }
    short8 abuf[2][2];
    abuf[0][0] = *(const short8*)(sA + arow0 + hi * 8);
    abuf[0][1] = *(const short8*)(sA + arow1 + hi * 8);
    #pragma unroll
    for (int step = 0; step < 16; step++) {
      if (step + 1 < 16) {
        abuf[(step + 1) & 1][0] = *(const short8*)(sA + arow0 + (step + 1) * 16 + hi * 8);
        abuf[(step + 1) & 1][1] = *(const short8*)(sA + arow1 + (step + 1) * 16 + hi * 8);
      }
      acc2[0][0] = __builtin_amdgcn_mfma_f32_32x32x16_bf16(abuf[step & 1][0], b2buf[step % 3][0], acc2[0][0], 0, 0, 0);
      acc2[0][1] = __builtin_amdgcn_mfma_f32_32x32x16_bf16(abuf[step & 1][0], b2buf[step % 3][1], acc2[0][1], 0, 0, 0);
      acc2[1][0] = __builtin_amdgcn_mfma_f32_32x32x16_bf16(abuf[step & 1][1], b2buf[step % 3][0], acc2[1][0], 0, 0, 0);
      acc2[1][1] = __builtin_amdgcn_mfma_f32_32x32x16_bf16(abuf[step & 1][1], b2buf[step % 3][1], acc2[1][1], 0, 0, 0);
      if (step + 3 < 16) {
        const short* bb = Wf2 + (size_t)((step + 3) * 2 + hi) * 2048;
        b2buf[step % 3][0] = *(const short8*)(bb + bc0);
        b2buf[step % 3][1] = *(const short8*)(bb + bc1);
      }
    }
  }

  __syncthreads();
  #pragma unroll
  for (int rg = 0; rg < 2; rg++)
    #pragma unroll
    for (int ct = 0; ct < 2; ct++) {
      int col = cb + ct * 32 + l31;
      float bv = b2[col];
      #pragma unroll
      for (int reg = 0; reg < 16; reg++) {
        int row = rg * 32 + (reg & 3) + 8 * (reg >> 2) + 4 * hi;
        sA[row * 264 + col] = f2bf(acc2[rg][ct][reg] + bv);
      }
    }
  __syncthreads();

  {
    int c = t;
    for (int r = 0; r < 64; ) {
      int nd = to_s[r];
      if (nd < 0) break;
      int re = rend_s[r];
      float a = 0.f;
      for (int i = r; i < re; i++)
        a += bf2f(sA[i * 264 + c]);
      float* dst = agg + (size_t)nd * 256 + c;
      if (inter_s[r]) *dst = a;
      else unsafeAtomicAdd(dst, a);
      r = re;
    }
  }
}

// ---------------- node update + fused P1/P2 for next step; zeroes agg ----------------
__global__ __launch_bounds__(256, 3) void update_mfma_p(
    float* __restrict__ h, short* __restrict__ hbf, float* __restrict__ agg,
    const short* __restrict__ Wfu, const float* __restrict__ bu,
    const short* __restrict__ Wf1a, const short* __restrict__ Wf1b,
    short* __restrict__ P1f, short* __restrict__ P2f, int want_p, int N)
{
  __shared__ short sA[32 * 392];

  int t = threadIdx.x;
  int ln = t & 63, w = t >> 6;
  int l31 = ln & 31, hi = ln >> 5;
  int n0 = blockIdx.x * 32;

  for (int i = t; i < 512; i += 256) {
    int r = i >> 4, c = i & 15;
    short8 v = {0, 0, 0, 0, 0, 0, 0, 0};
    if (n0 + r < N) v = *(const short8*)(hbf + (size_t)(n0 + r) * 128 + c * 8);
    *(short8*)(sA + r * 392 + c * 8) = v;
  }
  for (int i = t; i < 2048; i += 256) {
    int r = i >> 6, c4 = i & 63;
    int2 pk = {0, 0};
    if (n0 + r < N) {
      float4 v = *(const float4*)(agg + (size_t)(n0 + r) * 256 + c4 * 4);
      pk.x = (int)(unsigned short)f2bf(v.x) | ((int)(unsigned short)f2bf(v.y) << 16);
      pk.y = (int)(unsigned short)f2bf(v.z) | ((int)(unsigned short)f2bf(v.w) << 16);
    }
    *(int2*)(sA + r * 392 + 128 + c4 * 4) = pk;
  }
  __syncthreads();

  {
    float4 z = {0.f, 0.f, 0.f, 0.f};
    for (int i = t; i < 2048; i += 256) {
      int r = i >> 6, c4 = i & 63;
      if (n0 + r < N)
        *(float4*)(agg + (size_t)(n0 + r) * 256 + c4 * 4) = z;
    }
  }

  const int arow = l31 * 392;
  const int bcol = (w * 32 + l31) * 8;

  floatx16 acc;
  #pragma unroll
  for (int i = 0; i < 16; i++) acc[i] = 0.f;

  {
    short8 bbuf[3];
    #pragma unroll
    for (int s = 0; s < 3; s++)
      bbuf[s] = *(const short8*)(Wfu + (size_t)(s * 2 + hi) * 1024 + bcol);
    short8 abuf[2];
    abuf[0] = *(const short8*)(sA + arow + hi * 8);
    #pragma unroll
    for (int step = 0; step < 24; step++) {
      if (step + 1 < 24)
        abuf[(step + 1) & 1] = *(const short8*)(sA + arow + (step + 1) * 16 + hi * 8);
      acc = __builtin_amdgcn_mfma_f32_32x32x16_bf16(abuf[step & 1], bbuf[step % 3], acc, 0, 0, 0);
      if (step + 3 < 24)
        bbuf[step % 3] = *(const short8*)(Wfu + (size_t)((step + 3) * 2 + hi) * 1024 + bcol);
    }
  }

  __syncthreads();

  int col = w * 32 + l31;
  float bv = bu[col];
  #pragma unroll
  for (int reg = 0; reg < 16; reg++) {
    int row = (reg & 3) + 8 * (reg >> 2) + 4 * hi;
    int n = n0 + row;
    float nv = 0.f;
    if (n < N) nv = h[(size_t)n * 128 + col] + acc[reg] + bv;
    short bf = f2bf(nv);
    if (n < N) {
      h[(size_t)n * 128 + col] = nv;
      hbf[(size_t)n * 128 + col] = bf;
    }
    sA[row * 392 + col] = bf;
  }

  if (!want_p) return;
  __syncthreads();

  int cb = w * 64;
  const int bc0 = (cb + l31) * 8, bc1 = (cb + 32 + l31) * 8;
  floatx16 pacc[2][2];
  #pragma unroll
  for (int o = 0; o < 2; o++)
    #pragma unroll
    for (int ct = 0; ct < 2; ct++)
      #pragma unroll
      for (int i = 0; i < 16; i++) pacc[o][ct][i] = 0.f;

  #pragma unroll
  for (int step = 0; step < 8; step++) {
    short8 a = *(const short8*)(sA + arow + step * 16 + hi * 8);
    short8 ba0 = *(const short8*)(Wf1a + (size_t)(step * 2 + hi) * 2048 + bc0);
    short8 ba1 = *(const short8*)(Wf1a + (size_t)(step * 2 + hi) * 2048 + bc1);
    short8 bb0 = *(const short8*)(Wf1b + (size_t)(step * 2 + hi) * 2048 + bc0);
    short8 bb1 = *(const short8*)(Wf1b + (size_t)(step * 2 + hi) * 2048 + bc1);
    pacc[0][0] = __builtin_amdgcn_mfma_f32_32x32x16_bf16(a, ba0, pacc[0][0], 0, 0, 0);
    pacc[0][1] = __builtin_amdgcn_mfma_f32_32x32x16_bf16(a, ba1, pacc[0][1], 0, 0, 0);
    pacc[1][0] = __builtin_amdgcn_mfma_f32_32x32x16_bf16(a, bb0, pacc[1][0], 0, 0, 0);
    pacc[1][1] = __builtin_amdgcn_mfma_f32_32x32x16_bf16(a, bb1, pacc[1][1], 0, 0, 0);
  }

  #pragma unroll
  for (int ct = 0; ct < 2; ct++) {
    int pcol = cb + ct * 32 + l31;
    #pragma unroll
    for (int reg = 0; reg < 16; reg++) {
      int row = (reg & 3) + 8 * (reg >> 2) + 4 * hi;
      int n = n0 + row;
      if (n < N) {
        P1f[(size_t)n * 256 + pcol] = f2bf(pacc[0][ct][reg]);
        P2f[(size_t)n * 256 + pcol] = f2bf(pacc[1][ct][reg]);
      }
    }
  }
}

// ---------------- fused stack + attention features ----------------
__global__ __launch_bounds__(256, 3) void stack_attfeat(
    const float* __restrict__ h, const int* __restrict__ inv,
    const short* __restrict__ Wfa1, const float* __restrict__ ba1,
    const short* __restrict__ Wfa2, const float* __restrict__ ba2,
    const int* __restrict__ qsizes, const int* __restrict__ csizes,
    float* __restrict__ flat, short* __restrict__ flatT, short* __restrict__ tfb)
{
  __shared__ short sA[64 * 136];
  __shared__ int nd_s[64];

  int t = threadIdx.x;
  int ln = t & 63, w = t >> 6;
  int l31 = ln & 31, hi = ln >> 5;
  int r0 = blockIdx.x * 64;

  if (t < 64) nd_s[t] = inv[r0 + t];
  __syncthreads();

  for (int i = t; i < 1024; i += 256) {
    int r = i >> 4, c = (i & 15) * 8;
    int nd = nd_s[r];
    float4 v0 = {0.f, 0.f, 0.f, 0.f}, v1 = {0.f, 0.f, 0.f, 0.f};
    if (nd >= 0) {
      v0 = *(const float4*)(h + (size_t)nd * 128 + c);
      v1 = *(const float4*)(h + (size_t)nd * 128 + c + 4);
    }
    *(float4*)(flat + (size_t)(r0 + r) * 128 + c) = v0;
    *(float4*)(flat + (size_t)(r0 + r) * 128 + c + 4) = v1;
    short8 s;
    s[0] = f2bf(v0.x); s[1] = f2bf(v0.y); s[2] = f2bf(v0.z); s[3] = f2bf(v0.w);
    s[4] = f2bf(v1.x); s[5] = f2bf(v1.y); s[6] = f2bf(v1.z); s[7] = f2bf(v1.w);
    *(short8*)(sA + r * 136 + c) = s;
  }
  __syncthreads();

  for (int i = t; i < 8192; i += 256) {
    int d = i >> 6, r = i & 63;
    flatT[(size_t)blockIdx.x * 8192 + d * 64 + r] = sA[r * 136 + d];
  }

  const int arow0 = l31 * 136, arow1 = (32 + l31) * 136;
  const int bcol = (w * 32 + l31) * 8;
  int col = w * 32 + l31;

  floatx16 acc[2];
  #pragma unroll
  for (int rg = 0; rg < 2; rg++)
    #pragma unroll
    for (int i = 0; i < 16; i++) acc[rg][i] = 0.f;

  #pragma unroll
  for (int step = 0; step < 8; step++) {
    short8 a0 = *(const short8*)(sA + arow0 + step * 16 + hi * 8);
    short8 a1 = *(const short8*)(sA + arow1 + step * 16 + hi * 8);
    short8 bfr = *(const short8*)(Wfa1 + (size_t)(step * 2 + hi) * 1024 + bcol);
    acc[0] = __builtin_amdgcn_mfma_f32_32x32x16_bf16(a0, bfr, acc[0], 0, 0, 0);
    acc[1] = __builtin_amdgcn_mfma_f32_32x32x16_bf16(a1, bfr, acc[1], 0, 0, 0);
  }

  __syncthreads();
  {
    float bv = ba1[col];
    #pragma unroll
    for (int rg = 0; rg < 2; rg++)
      #pragma unroll
      for (int reg = 0; reg < 16; reg++) {
        int row = rg * 32 + (reg & 3) + 8 * (reg >> 2) + 4 * hi;
        sA[row * 136 + col] = f2bf(fmaxf(acc[rg][reg] + bv, 0.f));
      }
  }
  __syncthreads();

  floatx16 acc2[2];
  #pragma unroll
  for (int rg = 0; rg < 2; rg++)
    #pragma unroll
    for (int i = 0; i < 16; i++) acc2[rg][i] = 0.f;

  #pragma unroll
  for (int step = 0; step < 8; step++) {
    short8 a0 = *(const short8*)(sA + arow0 + step * 16 + hi * 8);
    short8 a1 = *(const short8*)(sA + arow1 + step * 16 + hi * 8);
    short8 bfr = *(const short8*)(Wfa2 + (size_t)(step * 2 + hi) * 1024 + bcol);
    acc2[0] = __builtin_amdgcn_mfma_f32_32x32x16_bf16(a0, bfr, acc2[0], 0, 0, 0);
    acc2[1] = __builtin_amdgcn_mfma_f32_32x32x16_bf16(a1, bfr, acc2[1], 0, 0, 0);
  }

  {
    float bv = ba2[col];
    #pragma unroll
    for (int rg = 0; rg < 2; rg++)
      #pragma unroll
      for (int reg = 0; reg < 16; reg++) {
        int row = r0 + rg * 32 + (reg & 3) + 8 * (reg >> 2) + 4 * hi;
        int part = row >> 14, b = (row >> 6) & 255, pp = row & 63;
        int sz = part ? csizes[b] : qsizes[b];
        float m = (pp < sz) ? 1.f : 0.f;
        tfb[(size_t)row * 128 + col] = f2bf((acc2[rg][reg] + bv) * m);
      }
  }
}

// ---------------- per-pair score: MFMA logits + MFMA PV ----------------
__global__ __launch_bounds__(256, 3) void score_kernel(
    const short* __restrict__ tfb, const float* __restrict__ flat,
    const short* __restrict__ flatT,
    const int* __restrict__ qsizes, const int* __restrict__ csizes,
    float* __restrict__ out)
{
  __shared__ float SL[64 * 65];
  __shared__ float SP2[64 * 65];
  __shared__ float red[8];

  int b = blockIdx.x, t = threadIdx.x;
  int ln = t & 63, w = t >> 6;
  int l31 = ln & 31, hi = ln >> 5;
  const short* tqb = tfb + (size_t)b * 8192;
  const short* tcb = tfb + (size_t)(256 + b) * 8192;
  const float* sq = flat + (size_t)b * 8192;
  const float* sc = flat + (size_t)(256 + b) * 8192;
  const short* sqT = flatT + (size_t)b * 8192;
  const short* scT = flatT + (size_t)(256 + b) * 8192;
  int qs = qsizes[b], cs = csizes[b];

  {
    int rowb = (w & 1) * 32, cbq = (w >> 1) * 32;
    floatx16 acc;
    #pragma unroll
    for (int i = 0; i < 16; i++) acc[i] = 0.f;
    #pragma unroll
    for (int step = 0; step < 8; step++) {
      short8 a  = *(const short8*)(tqb + (size_t)(rowb + l31) * 128 + step * 16 + hi * 8);
      short8 bf = *(const short8*)(tcb + (size_t)(cbq + l31) * 128 + step * 16 + hi * 8);
      acc = __builtin_amdgcn_mfma_f32_32x32x16_bf16(a, bf, acc, 0, 0, 0);
    }
    int ccol = cbq + l31;
    #pragma unroll
    for (int reg = 0; reg < 16; reg++) {
      int qrow = rowb + (reg & 3) + 8 * (reg >> 2) + 4 * hi;
      SL[qrow * 65 + ccol] = (qrow < qs && ccol < cs) ? acc[reg] * 10.0f : -1e9f;
    }
  }
  __syncthreads();

  float rmax = -1e30f, rsum = 0.f;
  if (t < 64) {
    int q = t;
    if (q < qs) {
      for (int c = 0; c < 64; c++) rmax = fmaxf(rmax, SL[q * 65 + c]);
      for (int c = 0; c < 64; c++) rsum += __expf(SL[q * 65 + c] - rmax);
    }
  } else if (t < 128) {
    int c = t - 64;
    if (c < cs) {
      float m = -1e30f;
      for (int q = 0; q < 64; q++) m = fmaxf(m, SL[q * 65 + c]);
      float s = 0.f;
      for (int q = 0; q < 64; q++) s += __expf(SL[q * 65 + c] - m);
      float inv = 1.0f / s;
      for (int q = 0; q < 64; q++) SP2[q * 65 + c] = __expf(SL[q * 65 + c] - m) * inv;
    } else {
      for (int q = 0; q < 64; q++) SP2[q * 65 + c] = 0.f;
    }
  }
  __syncthreads();

  if (t < 64) {
    int q = t;
    if (q < qs) {
      float inv = 1.0f / rsum;
      for (int c = 0; c < 64; c++) SL[q * 65 + c] = __expf(SL[q * 65 + c] - rmax) * inv;
    } else {
      for (int c = 0; c < 64; c++) SL[q * 65 + c] = 0.f;
    }
  }
  __syncthreads();

  int dcol = w * 32 + l31;
  floatx16 accq[2], accc[2];
  #pragma unroll
  for (int rt = 0; rt < 2; rt++) {
    #pragma unroll
    for (int i = 0; i < 16; i++) { accq[rt][i] = 0.f; accc[rt][i] = 0.f; }
  }

  #pragma unroll
  for (int rt = 0; rt < 2; rt++) {
    #pragma unroll
    for (int step = 0; step < 4; step++) {
      int kb = step * 16 + hi * 8;
      int row = rt * 32 + l31;
      short8 a;
      #pragma unroll
      for (int j = 0; j < 8; j++) a[j] = f2bf(SL[row * 65 + kb + j]);
      short8 bf = *(const short8*)(scT + (size_t)dcol * 64 + kb);
      accq[rt] = __builtin_amdgcn_mfma_f32_32x32x16_bf16(a, bf, accq[rt], 0, 0, 0);
    }
  }
  #pragma unroll
  for (int rt = 0; rt < 2; rt++) {
    #pragma unroll
    for (int step = 0; step < 4; step++) {
      int kb = step * 16 + hi * 8;
      int crow = rt * 32 + l31;
      short8 a;
      #pragma unroll
      for (int j = 0; j < 8; j++) a[j] = f2bf(SP2[(kb + j) * 65 + crow]);
      short8 bf = *(const short8*)(sqT + (size_t)dcol * 64 + kb);
      accc[rt] = __builtin_amdgcn_mfma_f32_32x32x16_bf16(a, bf, accc[rt], 0, 0, 0);
    }
  }

  float qpart = 0.f, cpart = 0.f;
  #pragma unroll
  for (int rt = 0; rt < 2; rt++) {
    #pragma unroll
    for (int reg = 0; reg < 16; reg++) {
      int row = rt * 32 + (reg & 3) + 8 * (reg >> 2) + 4 * hi;
      qpart += fmaxf(sq[(size_t)row * 128 + dcol] - accq[rt][reg], 0.f);
      cpart += fmaxf(sc[(size_t)row * 128 + dcol] - accc[rt][reg], 0.f);
    }
  }

  for (int off = 32; off > 0; off >>= 1) {
    qpart += __shfl_down(qpart, off);
    cpart += __shfl_down(cpart, off);
  }
  if ((t & 63) == 0) { red[w] = qpart; red[w + 4] = cpart; }
  __syncthreads();
  if (t == 0) {
    float qsum = red[0] + red[1] + red[2] + red[3];
    float csum = red[4] + red[5] + red[6] + red[7];
    out[b] = fminf(-qsum, -csum);
  }
}

// ---------------- launch ----------------
extern "C" void kernel_launch(void* const* d_in, const int* in_sizes, int n_in,
                              void* d_out, int out_size, void* d_ws, size_t ws_size,
                              hipStream_t stream)
{
  const float* nf  = (const float*)d_in[0];
  const float* ef  = (const float*)d_in[1];
  const int* from_idx = (const int*)d_in[2];
  const int* to_idx   = (const int*)d_in[3];
  const int* pos      = (const int*)d_in[4];
  const int* qsz      = (const int*)d_in[5];
  const int* csz      = (const int*)d_in[6];
  const float* W_node = (const float*)d_in[7];
  const float* b_node = (const float*)d_in[8];
  const float* W_edge = (const float*)d_in[9];
  const float* b_edge = (const float*)d_in[10];
  const float* W1 = (const float*)d_in[11];
  const float* b1 = (const float*)d_in[12];
  const float* W2 = (const float*)d_in[13];
  const float* b2 = (const float*)d_in[14];
  const float* Wu = (const float*)d_in[15];
  const float* bu = (const float*)d_in[16];
  const float* Wa1 = (const float*)d_in[17];
  const float* ba1 = (const float*)d_in[18];
  const float* Wa2 = (const float*)d_in[19];
  const float* ba2 = (const float*)d_in[20];
  float* out = (float*)d_out;

  int N = in_sizes[0] / NODE_F;
  int E = in_sizes[1] / EDGE_F;
  int Epad = (E + 63) & ~63;
  int PAD = 2 * B_PAIRS * MAXN;   // 32768

  float* h    = (float*)d_ws;                              // N*128 f32
  float* agg  = h + (size_t)N * D;                         // N*256 f32
  short* hb   = (short*)(agg + (size_t)N * 256);           // N*128 bf16
  short* P1f  = hb + (size_t)N * D;                        // N*256 bf16
  short* P2f  = P1f + (size_t)N * 256;                     // N*256 bf16
  short* Wfn  = P2f + (size_t)N * 256;                     // 4096
  short* Wfe  = Wfn + 4096;                                // 1024
  short* Wf1a = Wfe + 1024;                                // 32768
  short* Wf1b = Wf1a + 32768;                              // 32768
  short* Wf1e = Wf1b + 32768;                              // 16384
  short* Wf2  = Wf1e + 16384;                              // 65536
  short* Wfu  = Wf2 + 65536;                               // 49152
  short* Wfa1 = Wfu + 49152;                               // 16384
  short* Wfa2 = Wfa1 + 16384;                              // 16384
  int*   deg     = (int*)(Wfa2 + 16384);                   // N
  int*   offsets = deg + N;                                // N+1
  int*   cursor  = offsets + N + 1;                        // N
  int*   elist   = cursor + N;                             // E
  int*   inv     = elist + E;                              // PAD
  uintptr_t pb = ((uintptr_t)(inv + PAD) + 15) & ~(uintptr_t)15;
  short* ebF = (short*)pb;                                 // Epad*64 bf16 (fragment-major)
  float* flat  = (float*)(ebF + (size_t)Epad * 64);        // PAD*128 f32
  short* flatT = (short*)(flat + (size_t)PAD * D);         // PAD*128 bf16
  short* tfb16 = flatT + (size_t)PAD * D;                  // PAD*128 bf16

  hipMemsetAsync(deg, 0, (size_t)N * sizeof(int), stream);
  hist_kernel<<<256, 256, 0, stream>>>(to_idx, deg, inv, E);
  scan_kernel<<<1, 1024, 0, stream>>>(deg, offsets, cursor, pos, inv, N);
  scatter_csr<<<256, 256, 0, stream>>>(to_idx, cursor, elist, E);

  prep_w<<<916, 256, 0, stream>>>(W_node, W_edge, W1, W2, Wu, Wa1, Wa2,
                                  Wfn, Wfe, Wf1a, Wf1b, Wf1e, Wf2, Wfu, Wfa1, Wfa2);
  enc_nodes_p<<<(N + 31) / 32, 256, 0, stream>>>(nf, Wfn, b_node, h, hb,
                                                 Wf1a, Wf1b, P1f, P2f, N);
  enc_edges_f<<<Epad / 64, 256, 0, stream>>>(ef, elist, Wfe, b_edge, ebF, E);

  hipMemsetAsync(agg, 0, (size_t)N * 256 * sizeof(float), stream);

  for (int s = 0; s < PROP_STEPS; s++) {
    msg_mfma<<<Epad / 64, 256, 0, stream>>>(P1f, P2f, ebF, from_idx, to_idx, elist, offsets,
                                            Wf1e, b1, Wf2, b2, agg, E);
    update_mfma_p<<<(N + 31) / 32, 256, 0, stream>>>(h, hb, agg, Wfu, bu,
                                                     Wf1a, Wf1b, P1f, P2f,
                                                     (s + 1 < PROP_STEPS) ? 1 : 0, N);
  }

  stack_attfeat<<<PAD / 64, 256, 0, stream>>>(h, inv, Wfa1, ba1, Wfa2, ba2,
                                              qsz, csz, flat, flatT, tfb16);
  score_kernel<<<B_PAIRS, 256, 0, stream>>>(tfb16, flat, flatT, qsz, csz, out);
}

// Round 16
// 521.620 us; speedup vs baseline: 1.0168x; 1.0168x over previous
//
#include <hip/hip_runtime.h>

#define D 128
#define EDIM 64
#define NODE_F 32
#define EDGE_F 16
#define B_PAIRS 256
#define MAXN 64
#define PROP_STEPS 3

typedef __attribute__((ext_vector_type(4))) short short4v;
typedef __attribute__((ext_vector_type(8))) short short8;
typedef __attribute__((ext_vector_type(16))) float floatx16;

__device__ __forceinline__ short f2bf(float x) {
  unsigned u = __float_as_uint(x);
  u = (u + 0x7fff + ((u >> 16) & 1)) >> 16;   // RNE
  return (short)u;
}

__device__ __forceinline__ float bf2f(short s) {
  return __uint_as_float(((unsigned)(unsigned short)s) << 16);
}

// ---------------- fused weight prep + histogram + inv init (block-range) ----------------
// blocks 0..915: weight fragment conversion; blocks 916..1171: histogram + inv init.
__global__ __launch_bounds__(256) void init_kernel(
    const float* __restrict__ W_node, const float* __restrict__ W_edge,
    const float* __restrict__ W1, const float* __restrict__ W2,
    const float* __restrict__ Wu,
    const float* __restrict__ Wa1, const float* __restrict__ Wa2,
    short* __restrict__ Wfn, short* __restrict__ Wfe,
    short* __restrict__ Wf1a, short* __restrict__ Wf1b, short* __restrict__ Wf1e,
    short* __restrict__ Wf2, short* __restrict__ Wfu,
    short* __restrict__ Wfa1, short* __restrict__ Wfa2,
    const int* __restrict__ to_idx, int* __restrict__ deg,
    int* __restrict__ inv, int E)
{
  int bid = blockIdx.x;
  int t = threadIdx.x;
  if (bid >= 916) {
    int b2 = bid - 916;
    for (int e = b2 * 256 + t; e < E; e += 256 * 256)
      atomicAdd(&deg[to_idx[e]], 1);
    for (int i = b2 * 256 + t; i < 2 * B_PAIRS * MAXN; i += 256 * 256)
      inv[i] = -1;
    return;
  }
  int idx = bid * 256 + t;
  if (idx < 4096) {
    int step = idx >> 11, hi = (idx >> 10) & 1;
    int n = (idx >> 3) & 127, j = idx & 7;
    int k = step * 16 + hi * 8 + j;
    Wfn[idx] = f2bf(W_node[(size_t)k * 128 + n]);
  } else if (idx < 5120) {
    int i = idx - 4096;
    int hi = (i >> 9) & 1, n = (i >> 3) & 63, j = i & 7;
    int k = hi * 8 + j;
    Wfe[i] = f2bf(W_edge[(size_t)k * 64 + n]);
  } else if (idx < 37888) {
    int i = idx - 5120;
    int step = i >> 12, hi = (i >> 11) & 1;
    int n = (i >> 3) & 255, j = i & 7;
    int k = step * 16 + hi * 8 + j;
    Wf1a[i] = f2bf(W1[(size_t)k * 256 + n]);
  } else if (idx < 70656) {
    int i = idx - 37888;
    int step = i >> 12, hi = (i >> 11) & 1;
    int n = (i >> 3) & 255, j = i & 7;
    int k = step * 16 + hi * 8 + j;
    Wf1b[i] = f2bf(W1[(size_t)(128 + k) * 256 + n]);
  } else if (idx < 87040) {
    int i = idx - 70656;
    int step = i >> 12, hi = (i >> 11) & 1;
    int n = (i >> 3) & 255, j = i & 7;
    int k = step * 16 + hi * 8 + j;
    Wf1e[i] = f2bf(W1[(size_t)(256 + k) * 256 + n]);
  } else if (idx < 152576) {
    int i = idx - 87040;
    int step = i >> 12, hi = (i >> 11) & 1;
    int n = (i >> 3) & 255, j = i & 7;
    int k = step * 16 + hi * 8 + j;
    Wf2[i] = f2bf(W2[(size_t)k * 256 + n]);
  } else if (idx < 201728) {
    int i = idx - 152576;
    int step = i >> 11, hi = (i >> 10) & 1;
    int n = (i >> 3) & 127, j = i & 7;
    int k = step * 16 + hi * 8 + j;
    Wfu[i] = f2bf(Wu[(size_t)k * 128 + n]);
  } else if (idx < 218112) {
    int i = idx - 201728;
    int step = i >> 11, hi = (i >> 10) & 1;
    int n = (i >> 3) & 127, j = i & 7;
    int k = step * 16 + hi * 8 + j;
    Wfa1[i] = f2bf(Wa1[(size_t)k * 128 + n]);
  } else if (idx < 234496) {
    int i = idx - 218112;
    int step = i >> 11, hi = (i >> 10) & 1;
    int n = (i >> 3) & 127, j = i & 7;
    int k = step * 16 + hi * 8 + j;
    Wfa2[i] = f2bf(Wa2[(size_t)k * 128 + n]);
  }
}

// ---------------- scan + pos-inverse + boundary flags ----------------
__global__ __launch_bounds__(1024) void scan_kernel(const int* __restrict__ deg,
                                                    int* __restrict__ offsets,
                                                    int* __restrict__ cursor,
                                                    const int* __restrict__ pos,
                                                    int* __restrict__ inv,
                                                    int* __restrict__ zflag, int N)
{
  __shared__ int part[1024];
  int t = threadIdx.x;
  int chunk = (N + 1023) / 1024;
  int s0 = t * chunk, s1 = min(s0 + chunk, N);
  int sum = 0;
  for (int i = s0; i < s1; i++) sum += deg[i];
  part[t] = sum;
  __syncthreads();
  for (int off = 1; off < 1024; off <<= 1) {
    int v = 0;
    if (t >= off) v = part[t - off];
    __syncthreads();
    if (t >= off) part[t] += v;
    __syncthreads();
  }
  int base = (t == 0) ? 0 : part[t - 1];
  for (int i = s0; i < s1; i++) {
    int d = deg[i];
    offsets[i] = base; cursor[i] = base;
    // node needs zeroed agg iff it is aggregated via atomics (range spans a
    // 64-edge block boundary) or receives no writes at all (deg 0).
    zflag[i] = (d == 0) || ((base >> 6) != ((base + d - 1) >> 6)) ? 1 : 0;
    base += d;
  }
  if (t == 1023) offsets[N] = part[1023];
  for (int i = t; i < N; i += 1024) inv[pos[i]] = i;
}

__global__ __launch_bounds__(256) void scatter_csr(const int* __restrict__ to_idx,
                                                   int* __restrict__ cursor,
                                                   int* __restrict__ elist, int E)
{
  for (int e = blockIdx.x * 256 + threadIdx.x; e < E; e += gridDim.x * 256) {
    int pos = atomicAdd(&cursor[to_idx[e]], 1);
    elist[pos] = e;
  }
}

// ---------------- node encoder + fused P1/P2 ----------------
__global__ __launch_bounds__(256, 3) void enc_nodes_p(
    const float* __restrict__ nf, const short* __restrict__ Wfn,
    const float* __restrict__ b_node, float* __restrict__ h,
    short* __restrict__ hb,
    const short* __restrict__ Wf1a, const short* __restrict__ Wf1b,
    short* __restrict__ P1f, short* __restrict__ P2f, int N)
{
  __shared__ short sN[32 * 40];
  __shared__ short sH[32 * 136];
  int t = threadIdx.x;
  int ln = t & 63, w = t >> 6;
  int l31 = ln & 31, hi = ln >> 5;
  int n0 = blockIdx.x * 32;

  {
    int r = t >> 3, q = t & 7;
    float4 v = {0.f, 0.f, 0.f, 0.f};
    if (n0 + r < N) v = *(const float4*)(nf + (size_t)(n0 + r) * 32 + q * 4);
    short4v s;
    s[0] = f2bf(v.x); s[1] = f2bf(v.y); s[2] = f2bf(v.z); s[3] = f2bf(v.w);
    *(short4v*)(sN + r * 40 + q * 4) = s;
  }
  __syncthreads();

  int col = w * 32 + l31;
  {
    floatx16 acc;
    #pragma unroll
    for (int i = 0; i < 16; i++) acc[i] = 0.f;
    #pragma unroll
    for (int step = 0; step < 2; step++) {
      short8 a = *(const short8*)(sN + l31 * 40 + step * 16 + hi * 8);
      short8 b = *(const short8*)(Wfn + (size_t)(step * 2 + hi) * 1024 + col * 8);
      acc = __builtin_amdgcn_mfma_f32_32x32x16_bf16(a, b, acc, 0, 0, 0);
    }
    float bv = b_node[col];
    #pragma unroll
    for (int reg = 0; reg < 16; reg++) {
      int row = (reg & 3) + 8 * (reg >> 2) + 4 * hi;
      int n = n0 + row;
      float v = acc[reg] + bv;
      short bf = f2bf(v);
      if (n < N) {
        h[(size_t)n * 128 + col] = v;
        hb[(size_t)n * 128 + col] = bf;
      }
      sH[row * 136 + col] = bf;
    }
  }
  __syncthreads();

  int cb = w * 64;
  const int arow = l31 * 136;
  const int bc0 = (cb + l31) * 8, bc1 = (cb + 32 + l31) * 8;
  floatx16 acc[2][2];
  #pragma unroll
  for (int o = 0; o < 2; o++)
    #pragma unroll
    for (int ct = 0; ct < 2; ct++)
      #pragma unroll
      for (int i = 0; i < 16; i++) acc[o][ct][i] = 0.f;

  #pragma unroll
  for (int step = 0; step < 8; step++) {
    short8 a = *(const short8*)(sH + arow + step * 16 + hi * 8);
    short8 ba0 = *(const short8*)(Wf1a + (size_t)(step * 2 + hi) * 2048 + bc0);
    short8 ba1 = *(const short8*)(Wf1a + (size_t)(step * 2 + hi) * 2048 + bc1);
    short8 bb0 = *(const short8*)(Wf1b + (size_t)(step * 2 + hi) * 2048 + bc0);
    short8 bb1 = *(const short8*)(Wf1b + (size_t)(step * 2 + hi) * 2048 + bc1);
    acc[0][0] = __builtin_amdgcn_mfma_f32_32x32x16_bf16(a, ba0, acc[0][0], 0, 0, 0);
    acc[0][1] = __builtin_amdgcn_mfma_f32_32x32x16_bf16(a, ba1, acc[0][1], 0, 0, 0);
    acc[1][0] = __builtin_amdgcn_mfma_f32_32x32x16_bf16(a, bb0, acc[1][0], 0, 0, 0);
    acc[1][1] = __builtin_amdgcn_mfma_f32_32x32x16_bf16(a, bb1, acc[1][1], 0, 0, 0);
  }

  #pragma unroll
  for (int ct = 0; ct < 2; ct++) {
    int pcol = cb + ct * 32 + l31;
    #pragma unroll
    for (int reg = 0; reg < 16; reg++) {
      int row = (reg & 3) + 8 * (reg >> 2) + 4 * hi;
      int n = n0 + row;
      if (n < N) {
        P1f[(size_t)n * 256 + pcol] = f2bf(acc[0][ct][reg]);
        P2f[(size_t)n * 256 + pcol] = f2bf(acc[1][ct][reg]);
      }
    }
  }
}

// ---------------- fused edge encoder + Pe: Pe = (ef@We+be)@W1e + b1 (CSR-ordered) ----------------
__global__ __launch_bounds__(256, 4) void pe_fused(
    const float* __restrict__ ef, const int* __restrict__ elist,
    const short* __restrict__ Wfe, const float* __restrict__ b_edge,
    const short* __restrict__ Wf1e, const float* __restrict__ b1,
    short* __restrict__ Pe, int E)
{
  __shared__ short sE[64 * 24];
  __shared__ short sF[64 * 72];
  __shared__ int eid_s[64];

  int t = threadIdx.x;
  int ln = t & 63, w = t >> 6;
  int l31 = ln & 31, hi = ln >> 5;
  int e0 = blockIdx.x * 64;

  if (t < 64) eid_s[t] = (e0 + t < E) ? elist[e0 + t] : 0;
  __syncthreads();

  {
    int r = t >> 2, q = t & 3;
    float4 v = *(const float4*)(ef + (size_t)eid_s[r] * 16 + q * 4);
    short4v s;
    s[0] = f2bf(v.x); s[1] = f2bf(v.y); s[2] = f2bf(v.z); s[3] = f2bf(v.w);
    *(short4v*)(sE + r * 24 + q * 4) = s;
  }
  __syncthreads();

  {
    int rowb = (w & 1) * 32, cbq = (w >> 1) * 32;
    floatx16 acc;
    #pragma unroll
    for (int i = 0; i < 16; i++) acc[i] = 0.f;
    short8 a = *(const short8*)(sE + (rowb + l31) * 24 + hi * 8);
    short8 b = *(const short8*)(Wfe + (size_t)hi * 512 + (cbq + l31) * 8);
    acc = __builtin_amdgcn_mfma_f32_32x32x16_bf16(a, b, acc, 0, 0, 0);
    int col = cbq + l31;
    float bv = b_edge[col];
    #pragma unroll
    for (int reg = 0; reg < 16; reg++) {
      int row = rowb + (reg & 3) + 8 * (reg >> 2) + 4 * hi;
      sF[row * 72 + col] = f2bf(acc[reg] + bv);
    }
  }
  __syncthreads();

  const int cb = w * 64;
  const int bc0 = (cb + l31) * 8, bc1 = (cb + 32 + l31) * 8;
  floatx16 acc[2][2];
  #pragma unroll
  for (int rg = 0; rg < 2; rg++)
    #pragma unroll
    for (int ct = 0; ct < 2; ct++)
      #pragma unroll
      for (int i = 0; i < 16; i++) acc[rg][ct][i] = 0.f;

  #pragma unroll
  for (int step = 0; step < 4; step++) {
    short8 a0 = *(const short8*)(sF + l31 * 72 + step * 16 + hi * 8);
    short8 a1 = *(const short8*)(sF + (32 + l31) * 72 + step * 16 + hi * 8);
    short8 b0 = *(const short8*)(Wf1e + (size_t)(step * 2 + hi) * 2048 + bc0);
    short8 b1v = *(const short8*)(Wf1e + (size_t)(step * 2 + hi) * 2048 + bc1);
    acc[0][0] = __builtin_amdgcn_mfma_f32_32x32x16_bf16(a0, b0,  acc[0][0], 0, 0, 0);
    acc[0][1] = __builtin_amdgcn_mfma_f32_32x32x16_bf16(a0, b1v, acc[0][1], 0, 0, 0);
    acc[1][0] = __builtin_amdgcn_mfma_f32_32x32x16_bf16(a1, b0,  acc[1][0], 0, 0, 0);
    acc[1][1] = __builtin_amdgcn_mfma_f32_32x32x16_bf16(a1, b1v, acc[1][1], 0, 0, 0);
  }

  #pragma unroll
  for (int rg = 0; rg < 2; rg++)
    #pragma unroll
    for (int ct = 0; ct < 2; ct++) {
      int col = cb + ct * 32 + l31;
      float bv = b1[col];
      #pragma unroll
      for (int reg = 0; reg < 16; reg++) {
        int row = rg * 32 + (reg & 3) + 8 * (reg >> 2) + 4 * hi;
        Pe[(size_t)(e0 + row) * 256 + col] = f2bf(acc[rg][ct][reg] + bv);
      }
    }
}

// ---------------- message (R14 structure): relu(P1+P2+Pe) staging + GEMM2 + fused CSR agg ----------------
__global__ __launch_bounds__(256, 4) void msg_mfma(
    const short* __restrict__ P1f, const short* __restrict__ P2f,
    const short* __restrict__ Pe,
    const int* __restrict__ from_idx, const int* __restrict__ to_idx,
    const int* __restrict__ elist, const int* __restrict__ offsets,
    const short* __restrict__ Wf2, const float* __restrict__ b2,
    float* __restrict__ agg, int E)
{
  __shared__ short sA[64 * 264];
  __shared__ int from_s[64], to_s[64];
  __shared__ int rend_s[64], inter_s[64];

  int t = threadIdx.x;
  int ln = t & 63, w = t >> 6;
  int l31 = ln & 31, hi = ln >> 5;
  int cb = w * 64;
  int e0 = blockIdx.x * 64;

  if (t < 64) {
    int idx = e0 + t;
    int eid = (idx < E) ? elist[idx] : 0;
    from_s[t] = from_idx[eid];
    to_s[t] = (idx < E) ? to_idx[eid] : -1;
  }
  __syncthreads();

  if (t < 64) {
    int nd = to_s[t];
    bool head = (t == 0) || (nd != to_s[t - 1]);
    if (head && nd >= 0) {
      int re = t + 1;
      while (re < 64 && to_s[re] == nd) re++;
      rend_s[t] = re;
      inter_s[t] = (offsets[nd] == e0 + t) && (offsets[nd + 1] == e0 + re) ? 1 : 0;
    }
  }

  for (int i = t; i < 2048; i += 256) {
    int r = i >> 5, c8 = (i & 31) * 8;
    int nd = to_s[r]; if (nd < 0) nd = 0;
    short8 a = *(const short8*)(P1f + (size_t)from_s[r] * 256 + c8);
    short8 b = *(const short8*)(P2f + (size_t)nd * 256 + c8);
    short8 c = *(const short8*)(Pe + (size_t)(e0 + r) * 256 + c8);
    short8 o;
    #pragma unroll
    for (int j = 0; j < 8; j++)
      o[j] = f2bf(fmaxf(bf2f(a[j]) + bf2f(b[j]) + bf2f(c[j]), 0.f));
    *(short8*)(sA + r * 264 + c8) = o;
  }
  __syncthreads();

  const int arow0 = l31 * 264;
  const int arow1 = (32 + l31) * 264;
  const int bc0 = (cb + l31) * 8;
  const int bc1 = (cb + 32 + l31) * 8;

  floatx16 acc2[2][2];
  #pragma unroll
  for (int rg = 0; rg < 2; rg++)
    #pragma unroll
    for (int ct = 0; ct < 2; ct++)
      #pragma unroll
      for (int i = 0; i < 16; i++) acc2[rg][ct][i] = 0.f;

  {
    short8 b2buf[3][2];
    #pragma unroll
    for (int s = 0; s < 3; s++) {
      const short* bb = Wf2 + (size_t)(s * 2 + hi) * 2048;
      b2buf[s][0] = *(const short8*)(bb + bc0);
      b2buf[s][1] = *(const short8*)(bb + bc1);
    }
    short8 abuf[2][2];
    abuf[0][0] = *(const short8*)(sA + arow0 + hi * 8);
    abuf[0][1] = *(const short8*)(sA + arow1 + hi * 8);
    #pragma unroll
    for (int step = 0; step < 16; step++) {
      if (step + 1 < 16) {
        abuf[(step + 1) & 1][0] = *(const short8*)(sA + arow0 + (step + 1) * 16 + hi * 8);
        abuf[(step + 1) & 1][1] = *(const short8*)(sA + arow1 + (step + 1) * 16 + hi * 8);
      }
      acc2[0][0] = __builtin_amdgcn_mfma_f32_32x32x16_bf16(abuf[step & 1][0], b2buf[step % 3][0], acc2[0][0], 0, 0, 0);
      acc2[0][1] = __builtin_amdgcn_mfma_f32_32x32x16_bf16(abuf[step & 1][0], b2buf[step % 3][1], acc2[0][1], 0, 0, 0);
      acc2[1][0] = __builtin_amdgcn_mfma_f32_32x32x16_bf16(abuf[step & 1][1], b2buf[step % 3][0], acc2[1][0], 0, 0, 0);
      acc2[1][1] = __builtin_amdgcn_mfma_f32_32x32x16_bf16(abuf[step & 1][1], b2buf[step % 3][1], acc2[1][1], 0, 0, 0);
      if (step + 3 < 16) {
        const short* bb = Wf2 + (size_t)((step + 3) * 2 + hi) * 2048;
        b2buf[step % 3][0] = *(const short8*)(bb + bc0);
        b2buf[step % 3][1] = *(const short8*)(bb + bc1);
      }
    }
  }

  __syncthreads();
  #pragma unroll
  for (int rg = 0; rg < 2; rg++)
    #pragma unroll
    for (int ct = 0; ct < 2; ct++) {
      int col = cb + ct * 32 + l31;
      float bv = b2[col];
      #pragma unroll
      for (int reg = 0; reg < 16; reg++) {
        int row = rg * 32 + (reg & 3) + 8 * (reg >> 2) + 4 * hi;
        sA[row * 264 + col] = f2bf(acc2[rg][ct][reg] + bv);
      }
    }
  __syncthreads();

  {
    int c = t;
    for (int r = 0; r < 64; ) {
      int nd = to_s[r];
      if (nd < 0) break;
      int re = rend_s[r];
      float a = 0.f;
      for (int i = r; i < re; i++)
        a += bf2f(sA[i * 264 + c]);
      float* dst = agg + (size_t)nd * 256 + c;
      if (inter_s[r]) *dst = a;
      else unsafeAtomicAdd(dst, a);
      r = re;
    }
  }
}

// ---------------- node update + fused P1/P2; zeroes only boundary agg rows ----------------
__global__ __launch_bounds__(256, 3) void update_mfma_p(
    float* __restrict__ h, short* __restrict__ hbf, float* __restrict__ agg,
    const short* __restrict__ Wfu, const float* __restrict__ bu,
    const short* __restrict__ Wf1a, const short* __restrict__ Wf1b,
    short* __restrict__ P1f, short* __restrict__ P2f,
    const int* __restrict__ zflag, int want_p, int N)
{
  __shared__ short sA[32 * 392];
  __shared__ int zf_s[32];

  int t = threadIdx.x;
  int ln = t & 63, w = t >> 6;
  int l31 = ln & 31, hi = ln >> 5;
  int n0 = blockIdx.x * 32;

  if (t < 32) zf_s[t] = (n0 + t < N) ? zflag[n0 + t] : 0;

  for (int i = t; i < 512; i += 256) {
    int r = i >> 4, c = i & 15;
    short8 v = {0, 0, 0, 0, 0, 0, 0, 0};
    if (n0 + r < N) v = *(const short8*)(hbf + (size_t)(n0 + r) * 128 + c * 8);
    *(short8*)(sA + r * 392 + c * 8) = v;
  }
  for (int i = t; i < 2048; i += 256) {
    int r = i >> 6, c4 = i & 63;
    int2 pk = {0, 0};
    if (n0 + r < N) {
      float4 v = *(const float4*)(agg + (size_t)(n0 + r) * 256 + c4 * 4);
      pk.x = (int)(unsigned short)f2bf(v.x) | ((int)(unsigned short)f2bf(v.y) << 16);
      pk.y = (int)(unsigned short)f2bf(v.z) | ((int)(unsigned short)f2bf(v.w) << 16);
    }
    *(int2*)(sA + r * 392 + 128 + c4 * 4) = pk;
  }
  __syncthreads();

  // zero only atomically-aggregated (boundary/deg0) rows for the next step
  {
    float4 z = {0.f, 0.f, 0.f, 0.f};
    for (int i = t; i < 2048; i += 256) {
      int r = i >> 6, c4 = i & 63;
      if (n0 + r < N && zf_s[r])
        *(float4*)(agg + (size_t)(n0 + r) * 256 + c4 * 4) = z;
    }
  }

  const int arow = l31 * 392;
  const int bcol = (w * 32 + l31) * 8;

  floatx16 acc;
  #pragma unroll
  for (int i = 0; i < 16; i++) acc[i] = 0.f;

  {
    short8 bbuf[3];
    #pragma unroll
    for (int s = 0; s < 3; s++)
      bbuf[s] = *(const short8*)(Wfu + (size_t)(s * 2 + hi) * 1024 + bcol);
    short8 abuf[2];
    abuf[0] = *(const short8*)(sA + arow + hi * 8);
    #pragma unroll
    for (int step = 0; step < 24; step++) {
      if (step + 1 < 24)
        abuf[(step + 1) & 1] = *(const short8*)(sA + arow + (step + 1) * 16 + hi * 8);
      acc = __builtin_amdgcn_mfma_f32_32x32x16_bf16(abuf[step & 1], bbuf[step % 3], acc, 0, 0, 0);
      if (step + 3 < 24)
        bbuf[step % 3] = *(const short8*)(Wfu + (size_t)((step + 3) * 2 + hi) * 1024 + bcol);
    }
  }

  __syncthreads();

  int col = w * 32 + l31;
  float bv = bu[col];
  #pragma unroll
  for (int reg = 0; reg < 16; reg++) {
    int row = (reg & 3) + 8 * (reg >> 2) + 4 * hi;
    int n = n0 + row;
    float nv = 0.f;
    if (n < N) nv = h[(size_t)n * 128 + col] + acc[reg] + bv;
    short bf = f2bf(nv);
    if (n < N) {
      h[(size_t)n * 128 + col] = nv;
      hbf[(size_t)n * 128 + col] = bf;
    }
    sA[row * 392 + col] = bf;
  }

  if (!want_p) return;
  __syncthreads();

  int cb = w * 64;
  const int bc0 = (cb + l31) * 8, bc1 = (cb + 32 + l31) * 8;
  floatx16 pacc[2][2];
  #pragma unroll
  for (int o = 0; o < 2; o++)
    #pragma unroll
    for (int ct = 0; ct < 2; ct++)
      #pragma unroll
      for (int i = 0; i < 16; i++) pacc[o][ct][i] = 0.f;

  #pragma unroll
  for (int step = 0; step < 8; step++) {
    short8 a = *(const short8*)(sA + arow + step * 16 + hi * 8);
    short8 ba0 = *(const short8*)(Wf1a + (size_t)(step * 2 + hi) * 2048 + bc0);
    short8 ba1 = *(const short8*)(Wf1a + (size_t)(step * 2 + hi) * 2048 + bc1);
    short8 bb0 = *(const short8*)(Wf1b + (size_t)(step * 2 + hi) * 2048 + bc0);
    short8 bb1 = *(const short8*)(Wf1b + (size_t)(step * 2 + hi) * 2048 + bc1);
    pacc[0][0] = __builtin_amdgcn_mfma_f32_32x32x16_bf16(a, ba0, pacc[0][0], 0, 0, 0);
    pacc[0][1] = __builtin_amdgcn_mfma_f32_32x32x16_bf16(a, ba1, pacc[0][1], 0, 0, 0);
    pacc[1][0] = __builtin_amdgcn_mfma_f32_32x32x16_bf16(a, bb0, pacc[1][0], 0, 0, 0);
    pacc[1][1] = __builtin_amdgcn_mfma_f32_32x32x16_bf16(a, bb1, pacc[1][1], 0, 0, 0);
  }

  #pragma unroll
  for (int ct = 0; ct < 2; ct++) {
    int pcol = cb + ct * 32 + l31;
    #pragma unroll
    for (int reg = 0; reg < 16; reg++) {
      int row = (reg & 3) + 8 * (reg >> 2) + 4 * hi;
      int n = n0 + row;
      if (n < N) {
        P1f[(size_t)n * 256 + pcol] = f2bf(pacc[0][ct][reg]);
        P2f[(size_t)n * 256 + pcol] = f2bf(pacc[1][ct][reg]);
      }
    }
  }
}

// ---------------- fused stack + attention features ----------------
__global__ __launch_bounds__(256, 3) void stack_attfeat(
    const float* __restrict__ h, const int* __restrict__ inv,
    const short* __restrict__ Wfa1, const float* __restrict__ ba1,
    const short* __restrict__ Wfa2, const float* __restrict__ ba2,
    const int* __restrict__ qsizes, const int* __restrict__ csizes,
    float* __restrict__ flat, short* __restrict__ flatT, short* __restrict__ tfb)
{
  __shared__ short sA[64 * 136];
  __shared__ int nd_s[64];

  int t = threadIdx.x;
  int ln = t & 63, w = t >> 6;
  int l31 = ln & 31, hi = ln >> 5;
  int r0 = blockIdx.x * 64;

  if (t < 64) nd_s[t] = inv[r0 + t];
  __syncthreads();

  for (int i = t; i < 1024; i += 256) {
    int r = i >> 4, c = (i & 15) * 8;
    int nd = nd_s[r];
    float4 v0 = {0.f, 0.f, 0.f, 0.f}, v1 = {0.f, 0.f, 0.f, 0.f};
    if (nd >= 0) {
      v0 = *(const float4*)(h + (size_t)nd * 128 + c);
      v1 = *(const float4*)(h + (size_t)nd * 128 + c + 4);
    }
    *(float4*)(flat + (size_t)(r0 + r) * 128 + c) = v0;
    *(float4*)(flat + (size_t)(r0 + r) * 128 + c + 4) = v1;
    short8 s;
    s[0] = f2bf(v0.x); s[1] = f2bf(v0.y); s[2] = f2bf(v0.z); s[3] = f2bf(v0.w);
    s[4] = f2bf(v1.x); s[5] = f2bf(v1.y); s[6] = f2bf(v1.z); s[7] = f2bf(v1.w);
    *(short8*)(sA + r * 136 + c) = s;
  }
  __syncthreads();

  for (int i = t; i < 8192; i += 256) {
    int d = i >> 6, r = i & 63;
    flatT[(size_t)blockIdx.x * 8192 + d * 64 + r] = sA[r * 136 + d];
  }

  const int arow0 = l31 * 136, arow1 = (32 + l31) * 136;
  const int bcol = (w * 32 + l31) * 8;
  int col = w * 32 + l31;

  floatx16 acc[2];
  #pragma unroll
  for (int rg = 0; rg < 2; rg++)
    #pragma unroll
    for (int i = 0; i < 16; i++) acc[rg][i] = 0.f;

  #pragma unroll
  for (int step = 0; step < 8; step++) {
    short8 a0 = *(const short8*)(sA + arow0 + step * 16 + hi * 8);
    short8 a1 = *(const short8*)(sA + arow1 + step * 16 + hi * 8);
    short8 bfr = *(const short8*)(Wfa1 + (size_t)(step * 2 + hi) * 1024 + bcol);
    acc[0] = __builtin_amdgcn_mfma_f32_32x32x16_bf16(a0, bfr, acc[0], 0, 0, 0);
    acc[1] = __builtin_amdgcn_mfma_f32_32x32x16_bf16(a1, bfr, acc[1], 0, 0, 0);
  }

  __syncthreads();
  {
    float bv = ba1[col];
    #pragma unroll
    for (int rg = 0; rg < 2; rg++)
      #pragma unroll
      for (int reg = 0; reg < 16; reg++) {
        int row = rg * 32 + (reg & 3) + 8 * (reg >> 2) + 4 * hi;
        sA[row * 136 + col] = f2bf(fmaxf(acc[rg][reg] + bv, 0.f));
      }
  }
  __syncthreads();

  floatx16 acc2[2];
  #pragma unroll
  for (int rg = 0; rg < 2; rg++)
    #pragma unroll
    for (int i = 0; i < 16; i++) acc2[rg][i] = 0.f;

  #pragma unroll
  for (int step = 0; step < 8; step++) {
    short8 a0 = *(const short8*)(sA + arow0 + step * 16 + hi * 8);
    short8 a1 = *(const short8*)(sA + arow1 + step * 16 + hi * 8);
    short8 bfr = *(const short8*)(Wfa2 + (size_t)(step * 2 + hi) * 1024 + bcol);
    acc2[0] = __builtin_amdgcn_mfma_f32_32x32x16_bf16(a0, bfr, acc2[0], 0, 0, 0);
    acc2[1] = __builtin_amdgcn_mfma_f32_32x32x16_bf16(a1, bfr, acc2[1], 0, 0, 0);
  }

  {
    float bv = ba2[col];
    #pragma unroll
    for (int rg = 0; rg < 2; rg++)
      #pragma unroll
      for (int reg = 0; reg < 16; reg++) {
        int row = r0 + rg * 32 + (reg & 3) + 8 * (reg >> 2) + 4 * hi;
        int part = row >> 14, b = (row >> 6) & 255, pp = row & 63;
        int sz = part ? csizes[b] : qsizes[b];
        float m = (pp < sz) ? 1.f : 0.f;
        tfb[(size_t)row * 128 + col] = f2bf((acc2[rg][reg] + bv) * m);
      }
  }
}

// ---------------- per-pair score: MFMA logits + MFMA PV ----------------
__global__ __launch_bounds__(256, 3) void score_kernel(
    const short* __restrict__ tfb, const float* __restrict__ flat,
    const short* __restrict__ flatT,
    const int* __restrict__ qsizes, const int* __restrict__ csizes,
    float* __restrict__ out)
{
  __shared__ float SL[64 * 65];
  __shared__ float SP2[64 * 65];
  __shared__ float red[8];

  int b = blockIdx.x, t = threadIdx.x;
  int ln = t & 63, w = t >> 6;
  int l31 = ln & 31, hi = ln >> 5;
  const short* tqb = tfb + (size_t)b * 8192;
  const short* tcb = tfb + (size_t)(256 + b) * 8192;
  const float* sq = flat + (size_t)b * 8192;
  const float* sc = flat + (size_t)(256 + b) * 8192;
  const short* sqT = flatT + (size_t)b * 8192;
  const short* scT = flatT + (size_t)(256 + b) * 8192;
  int qs = qsizes[b], cs = csizes[b];

  {
    int rowb = (w & 1) * 32, cbq = (w >> 1) * 32;
    floatx16 acc;
    #pragma unroll
    for (int i = 0; i < 16; i++) acc[i] = 0.f;
    #pragma unroll
    for (int step = 0; step < 8; step++) {
      short8 a  = *(const short8*)(tqb + (size_t)(rowb + l31) * 128 + step * 16 + hi * 8);
      short8 bf = *(const short8*)(tcb + (size_t)(cbq + l31) * 128 + step * 16 + hi * 8);
      acc = __builtin_amdgcn_mfma_f32_32x32x16_bf16(a, bf, acc, 0, 0, 0);
    }
    int ccol = cbq + l31;
    #pragma unroll
    for (int reg = 0; reg < 16; reg++) {
      int qrow = rowb + (reg & 3) + 8 * (reg >> 2) + 4 * hi;
      SL[qrow * 65 + ccol] = (qrow < qs && ccol < cs) ? acc[reg] * 10.0f : -1e9f;
    }
  }
  __syncthreads();

  float rmax = -1e30f, rsum = 0.f;
  if (t < 64) {
    int q = t;
    if (q < qs) {
      for (int c = 0; c < 64; c++) rmax = fmaxf(rmax, SL[q * 65 + c]);
      for (int c = 0; c < 64; c++) rsum += __expf(SL[q * 65 + c] - rmax);
    }
  } else if (t < 128) {
    int c = t - 64;
    if (c < cs) {
      float m = -1e30f;
      for (int q = 0; q < 64; q++) m = fmaxf(m, SL[q * 65 + c]);
      float s = 0.f;
      for (int q = 0; q < 64; q++) s += __expf(SL[q * 65 + c] - m);
      float inv = 1.0f / s;
      for (int q = 0; q < 64; q++) SP2[q * 65 + c] = __expf(SL[q * 65 + c] - m) * inv;
    } else {
      for (int q = 0; q < 64; q++) SP2[q * 65 + c] = 0.f;
    }
  }
  __syncthreads();

  if (t < 64) {
    int q = t;
    if (q < qs) {
      float inv = 1.0f / rsum;
      for (int c = 0; c < 64; c++) SL[q * 65 + c] = __expf(SL[q * 65 + c] - rmax) * inv;
    } else {
      for (int c = 0; c < 64; c++) SL[q * 65 + c] = 0.f;
    }
  }
  __syncthreads();

  int dcol = w * 32 + l31;
  floatx16 accq[2], accc[2];
  #pragma unroll
  for (int rt = 0; rt < 2; rt++) {
    #pragma unroll
    for (int i = 0; i < 16; i++) { accq[rt][i] = 0.f; accc[rt][i] = 0.f; }
  }

  #pragma unroll
  for (int rt = 0; rt < 2; rt++) {
    #pragma unroll
    for (int step = 0; step < 4; step++) {
      int kb = step * 16 + hi * 8;
      int row = rt * 32 + l31;
      short8 a;
      #pragma unroll
      for (int j = 0; j < 8; j++) a[j] = f2bf(SL[row * 65 + kb + j]);
      short8 bf = *(const short8*)(scT + (size_t)dcol * 64 + kb);
      accq[rt] = __builtin_amdgcn_mfma_f32_32x32x16_bf16(a, bf, accq[rt], 0, 0, 0);
    }
  }
  #pragma unroll
  for (int rt = 0; rt < 2; rt++) {
    #pragma unroll
    for (int step = 0; step < 4; step++) {
      int kb = step * 16 + hi * 8;
      int crow = rt * 32 + l31;
      short8 a;
      #pragma unroll
      for (int j = 0; j < 8; j++) a[j] = f2bf(SP2[(kb + j) * 65 + crow]);
      short8 bf = *(const short8*)(sqT + (size_t)dcol * 64 + kb);
      accc[rt] = __builtin_amdgcn_mfma_f32_32x32x16_bf16(a, bf, accc[rt], 0, 0, 0);
    }
  }

  float qpart = 0.f, cpart = 0.f;
  #pragma unroll
  for (int rt = 0; rt < 2; rt++) {
    #pragma unroll
    for (int reg = 0; reg < 16; reg++) {
      int row = rt * 32 + (reg & 3) + 8 * (reg >> 2) + 4 * hi;
      qpart += fmaxf(sq[(size_t)row * 128 + dcol] - accq[rt][reg], 0.f);
      cpart += fmaxf(sc[(size_t)row * 128 + dcol] - accc[rt][reg], 0.f);
    }
  }

  for (int off = 32; off > 0; off >>= 1) {
    qpart += __shfl_down(qpart, off);
    cpart += __shfl_down(cpart, off);
  }
  if ((t & 63) == 0) { red[w] = qpart; red[w + 4] = cpart; }
  __syncthreads();
  if (t == 0) {
    float qsum = red[0] + red[1] + red[2] + red[3];
    float csum = red[4] + red[5] + red[6] + red[7];
    out[b] = fminf(-qsum, -csum);
  }
}

// ---------------- launch ----------------
extern "C" void kernel_launch(void* const* d_in, const int* in_sizes, int n_in,
                              void* d_out, int out_size, void* d_ws, size_t ws_size,
                              hipStream_t stream)
{
  const float* nf  = (const float*)d_in[0];
  const float* ef  = (const float*)d_in[1];
  const int* from_idx = (const int*)d_in[2];
  const int* to_idx   = (const int*)d_in[3];
  const int* pos      = (const int*)d_in[4];
  const int* qsz      = (const int*)d_in[5];
  const int* csz      = (const int*)d_in[6];
  const float* W_node = (const float*)d_in[7];
  const float* b_node = (const float*)d_in[8];
  const float* W_edge = (const float*)d_in[9];
  const float* b_edge = (const float*)d_in[10];
  const float* W1 = (const float*)d_in[11];
  const float* b1 = (const float*)d_in[12];
  const float* W2 = (const float*)d_in[13];
  const float* b2 = (const float*)d_in[14];
  const float* Wu = (const float*)d_in[15];
  const float* bu = (const float*)d_in[16];
  const float* Wa1 = (const float*)d_in[17];
  const float* ba1 = (const float*)d_in[18];
  const float* Wa2 = (const float*)d_in[19];
  const float* ba2 = (const float*)d_in[20];
  float* out = (float*)d_out;

  int N = in_sizes[0] / NODE_F;
  int E = in_sizes[1] / EDGE_F;
  int Epad = (E + 63) & ~63;
  int PAD = 2 * B_PAIRS * MAXN;   // 32768

  float* h    = (float*)d_ws;                              // N*128 f32
  float* agg  = h + (size_t)N * D;                         // N*256 f32
  short* hb   = (short*)(agg + (size_t)N * 256);           // N*128 bf16
  short* P1f  = hb + (size_t)N * D;                        // N*256 bf16
  short* P2f  = P1f + (size_t)N * 256;                     // N*256 bf16
  short* Wfn  = P2f + (size_t)N * 256;                     // 4096
  short* Wfe  = Wfn + 4096;                                // 1024
  short* Wf1a = Wfe + 1024;                                // 32768
  short* Wf1b = Wf1a + 32768;                              // 32768
  short* Wf1e = Wf1b + 32768;                              // 16384
  short* Wf2  = Wf1e + 16384;                              // 65536
  short* Wfu  = Wf2 + 65536;                               // 49152
  short* Wfa1 = Wfu + 49152;                               // 16384
  short* Wfa2 = Wfa1 + 16384;                              // 16384
  int*   deg     = (int*)(Wfa2 + 16384);                   // N
  int*   offsets = deg + N;                                // N+1
  int*   cursor  = offsets + N + 1;                        // N
  int*   elist   = cursor + N;                             // E
  int*   inv     = elist + E;                              // PAD
  int*   zflag   = inv + PAD;                              // N
  uintptr_t pb = ((uintptr_t)(zflag + N) + 15) & ~(uintptr_t)15;
  short* Pe = (short*)pb;                                  // Epad*256 bf16 (CSR order)
  // flat group aliases Pe (Pe dead after prop loop; 33.6MB <= Pe's ~101MB)
  float* flat  = (float*)Pe;
  short* flatT = (short*)(flat + (size_t)PAD * D);
  short* tfb16 = flatT + (size_t)PAD * D;

  hipMemsetAsync(deg, 0, (size_t)N * sizeof(int), stream);
  init_kernel<<<916 + 256, 256, 0, stream>>>(
      W_node, W_edge, W1, W2, Wu, Wa1, Wa2,
      Wfn, Wfe, Wf1a, Wf1b, Wf1e, Wf2, Wfu, Wfa1, Wfa2,
      to_idx, deg, inv, E);
  scan_kernel<<<1, 1024, 0, stream>>>(deg, offsets, cursor, pos, inv, zflag, N);
  scatter_csr<<<256, 256, 0, stream>>>(to_idx, cursor, elist, E);

  enc_nodes_p<<<(N + 31) / 32, 256, 0, stream>>>(nf, Wfn, b_node, h, hb,
                                                 Wf1a, Wf1b, P1f, P2f, N);
  pe_fused<<<Epad / 64, 256, 0, stream>>>(ef, elist, Wfe, b_edge, Wf1e, b1, Pe, E);

  hipMemsetAsync(agg, 0, (size_t)N * 256 * sizeof(float), stream);

  for (int s = 0; s < PROP_STEPS; s++) {
    msg_mfma<<<Epad / 64, 256, 0, stream>>>(P1f, P2f, Pe, from_idx, to_idx, elist, offsets,
                                            Wf2, b2, agg, E);
    update_mfma_p<<<(N + 31) / 32, 256, 0, stream>>>(h, hb, agg, Wfu, bu,
                                                     Wf1a, Wf1b, P1f, P2f, zflag,
                                                     (s + 1 < PROP_STEPS) ? 1 : 0, N);
  }

  stack_attfeat<<<PAD / 64, 256, 0, stream>>>(h, inv, Wfa1, ba1, Wfa2, ba2,
                                              qsz, csz, flat, flatT, tfb16);
  score_kernel<<<B_PAIRS, 256, 0, stream>>>(tfb16, flat, flatT, qsz, csz, out);
}

// Round 17
// 470.938 us; speedup vs baseline: 1.1262x; 1.1076x over previous
//
#include <hip/hip_runtime.h>

#define D 128
#define EDIM 64
#define NODE_F 32
#define EDGE_F 16
#define B_PAIRS 256
#define MAXN 64
#define PROP_STEPS 3

typedef __attribute__((ext_vector_type(4))) short short4v;
typedef __attribute__((ext_vector_type(8))) short short8;
typedef __attribute__((ext_vector_type(16))) float floatx16;

__device__ __forceinline__ short f2bf(float x) {
  unsigned u = __float_as_uint(x);
  u = (u + 0x7fff + ((u >> 16) & 1)) >> 16;   // RNE
  return (short)u;
}

__device__ __forceinline__ float bf2f(short s) {
  return __uint_as_float(((unsigned)(unsigned short)s) << 16);
}

// ---------------- fused weight prep + histogram + inv init (block-range) ----------------
__global__ __launch_bounds__(256) void init_kernel(
    const float* __restrict__ W_node, const float* __restrict__ W_edge,
    const float* __restrict__ W1, const float* __restrict__ W2,
    const float* __restrict__ Wu,
    const float* __restrict__ Wa1, const float* __restrict__ Wa2,
    short* __restrict__ Wfn, short* __restrict__ Wfe,
    short* __restrict__ Wf1a, short* __restrict__ Wf1b, short* __restrict__ Wf1e,
    short* __restrict__ Wf2, short* __restrict__ Wfu,
    short* __restrict__ Wfa1, short* __restrict__ Wfa2,
    const int* __restrict__ to_idx, int* __restrict__ deg,
    int* __restrict__ inv, int E)
{
  int bid = blockIdx.x;
  int t = threadIdx.x;
  if (bid >= 916) {
    int b2 = bid - 916;
    for (int e = b2 * 256 + t; e < E; e += 256 * 256)
      atomicAdd(&deg[to_idx[e]], 1);
    for (int i = b2 * 256 + t; i < 2 * B_PAIRS * MAXN; i += 256 * 256)
      inv[i] = -1;
    return;
  }
  int idx = bid * 256 + t;
  if (idx < 4096) {
    int step = idx >> 11, hi = (idx >> 10) & 1;
    int n = (idx >> 3) & 127, j = idx & 7;
    int k = step * 16 + hi * 8 + j;
    Wfn[idx] = f2bf(W_node[(size_t)k * 128 + n]);
  } else if (idx < 5120) {
    int i = idx - 4096;
    int hi = (i >> 9) & 1, n = (i >> 3) & 63, j = i & 7;
    int k = hi * 8 + j;
    Wfe[i] = f2bf(W_edge[(size_t)k * 64 + n]);
  } else if (idx < 37888) {
    int i = idx - 5120;
    int step = i >> 12, hi = (i >> 11) & 1;
    int n = (i >> 3) & 255, j = i & 7;
    int k = step * 16 + hi * 8 + j;
    Wf1a[i] = f2bf(W1[(size_t)k * 256 + n]);
  } else if (idx < 70656) {
    int i = idx - 37888;
    int step = i >> 12, hi = (i >> 11) & 1;
    int n = (i >> 3) & 255, j = i & 7;
    int k = step * 16 + hi * 8 + j;
    Wf1b[i] = f2bf(W1[(size_t)(128 + k) * 256 + n]);
  } else if (idx < 87040) {
    int i = idx - 70656;
    int step = i >> 12, hi = (i >> 11) & 1;
    int n = (i >> 3) & 255, j = i & 7;
    int k = step * 16 + hi * 8 + j;
    Wf1e[i] = f2bf(W1[(size_t)(256 + k) * 256 + n]);
  } else if (idx < 152576) {
    int i = idx - 87040;
    int step = i >> 12, hi = (i >> 11) & 1;
    int n = (i >> 3) & 255, j = i & 7;
    int k = step * 16 + hi * 8 + j;
    Wf2[i] = f2bf(W2[(size_t)k * 256 + n]);
  } else if (idx < 201728) {
    int i = idx - 152576;
    int step = i >> 11, hi = (i >> 10) & 1;
    int n = (i >> 3) & 127, j = i & 7;
    int k = step * 16 + hi * 8 + j;
    Wfu[i] = f2bf(Wu[(size_t)k * 128 + n]);
  } else if (idx < 218112) {
    int i = idx - 201728;
    int step = i >> 11, hi = (i >> 10) & 1;
    int n = (i >> 3) & 127, j = i & 7;
    int k = step * 16 + hi * 8 + j;
    Wfa1[i] = f2bf(Wa1[(size_t)k * 128 + n]);
  } else if (idx < 234496) {
    int i = idx - 218112;
    int step = i >> 11, hi = (i >> 10) & 1;
    int n = (i >> 3) & 127, j = i & 7;
    int k = step * 16 + hi * 8 + j;
    Wfa2[i] = f2bf(Wa2[(size_t)k * 128 + n]);
  }
}

// ---------------- parallel 3-phase CSR scan ----------------
// scan1: per-block sums of deg (1024 nodes/block)
__global__ __launch_bounds__(1024) void scan1(const int* __restrict__ deg,
                                              int* __restrict__ partials, int N)
{
  __shared__ int red[16];
  int t = threadIdx.x;
  int n = blockIdx.x * 1024 + t;
  int v = (n < N) ? deg[n] : 0;
  for (int off = 32; off > 0; off >>= 1) v += __shfl_down(v, off);
  if ((t & 63) == 0) red[t >> 6] = v;
  __syncthreads();
  if (t == 0) {
    int s = 0;
    #pragma unroll
    for (int i = 0; i < 16; i++) s += red[i];
    partials[blockIdx.x] = s;
  }
}

// scan2: exclusive scan of B block sums (B <= 64); writes offsets[N]=total
__global__ __launch_bounds__(64) void scan2(int* __restrict__ partials,
                                            int* __restrict__ offsets, int B, int N)
{
  __shared__ int sp[64];
  int t = threadIdx.x;
  sp[t] = (t < B) ? partials[t] : 0;
  __syncthreads();
  if (t == 0) {
    int run = 0;
    for (int i = 0; i < B; i++) { int v = sp[i]; sp[i] = run; run += v; }
    offsets[N] = run;
  }
  __syncthreads();
  if (t < B) partials[t] = sp[t];
}

// scan3: per-node offsets via 1024-wide LDS scan + block base; cursor, zflag, inv
__global__ __launch_bounds__(1024) void scan3(const int* __restrict__ deg,
                                              const int* __restrict__ partials,
                                              int* __restrict__ offsets,
                                              int* __restrict__ cursor,
                                              int* __restrict__ zflag,
                                              const int* __restrict__ pos,
                                              int* __restrict__ inv, int N)
{
  __shared__ int s[1024];
  int t = threadIdx.x;
  int n = blockIdx.x * 1024 + t;
  int d = (n < N) ? deg[n] : 0;
  s[t] = d;
  __syncthreads();
  for (int off = 1; off < 1024; off <<= 1) {
    int v = 0;
    if (t >= off) v = s[t - off];
    __syncthreads();
    if (t >= off) s[t] += v;
    __syncthreads();
  }
  if (n < N) {
    int off = partials[blockIdx.x] + s[t] - d;   // exclusive prefix
    offsets[n] = off; cursor[n] = off;
    zflag[n] = (d == 0) || ((off >> 6) != ((off + d - 1) >> 6)) ? 1 : 0;
    inv[pos[n]] = n;
  }
}

__global__ __launch_bounds__(256) void scatter_csr(const int* __restrict__ to_idx,
                                                   int* __restrict__ cursor,
                                                   int* __restrict__ elist, int E)
{
  for (int e = blockIdx.x * 256 + threadIdx.x; e < E; e += gridDim.x * 256) {
    int pos = atomicAdd(&cursor[to_idx[e]], 1);
    elist[pos] = e;
  }
}

// ---------------- node encoder + fused P1/P2 ----------------
__global__ __launch_bounds__(256, 3) void enc_nodes_p(
    const float* __restrict__ nf, const short* __restrict__ Wfn,
    const float* __restrict__ b_node, float* __restrict__ h,
    short* __restrict__ hb,
    const short* __restrict__ Wf1a, const short* __restrict__ Wf1b,
    short* __restrict__ P1f, short* __restrict__ P2f, int N)
{
  __shared__ short sN[32 * 40];
  __shared__ short sH[32 * 136];
  int t = threadIdx.x;
  int ln = t & 63, w = t >> 6;
  int l31 = ln & 31, hi = ln >> 5;
  int n0 = blockIdx.x * 32;

  {
    int r = t >> 3, q = t & 7;
    float4 v = {0.f, 0.f, 0.f, 0.f};
    if (n0 + r < N) v = *(const float4*)(nf + (size_t)(n0 + r) * 32 + q * 4);
    short4v s;
    s[0] = f2bf(v.x); s[1] = f2bf(v.y); s[2] = f2bf(v.z); s[3] = f2bf(v.w);
    *(short4v*)(sN + r * 40 + q * 4) = s;
  }
  __syncthreads();

  int col = w * 32 + l31;
  {
    floatx16 acc;
    #pragma unroll
    for (int i = 0; i < 16; i++) acc[i] = 0.f;
    #pragma unroll
    for (int step = 0; step < 2; step++) {
      short8 a = *(const short8*)(sN + l31 * 40 + step * 16 + hi * 8);
      short8 b = *(const short8*)(Wfn + (size_t)(step * 2 + hi) * 1024 + col * 8);
      acc = __builtin_amdgcn_mfma_f32_32x32x16_bf16(a, b, acc, 0, 0, 0);
    }
    float bv = b_node[col];
    #pragma unroll
    for (int reg = 0; reg < 16; reg++) {
      int row = (reg & 3) + 8 * (reg >> 2) + 4 * hi;
      int n = n0 + row;
      float v = acc[reg] + bv;
      short bf = f2bf(v);
      if (n < N) {
        h[(size_t)n * 128 + col] = v;
        hb[(size_t)n * 128 + col] = bf;
      }
      sH[row * 136 + col] = bf;
    }
  }
  __syncthreads();

  int cb = w * 64;
  const int arow = l31 * 136;
  const int bc0 = (cb + l31) * 8, bc1 = (cb + 32 + l31) * 8;
  floatx16 acc[2][2];
  #pragma unroll
  for (int o = 0; o < 2; o++)
    #pragma unroll
    for (int ct = 0; ct < 2; ct++)
      #pragma unroll
      for (int i = 0; i < 16; i++) acc[o][ct][i] = 0.f;

  #pragma unroll
  for (int step = 0; step < 8; step++) {
    short8 a = *(const short8*)(sH + arow + step * 16 + hi * 8);
    short8 ba0 = *(const short8*)(Wf1a + (size_t)(step * 2 + hi) * 2048 + bc0);
    short8 ba1 = *(const short8*)(Wf1a + (size_t)(step * 2 + hi) * 2048 + bc1);
    short8 bb0 = *(const short8*)(Wf1b + (size_t)(step * 2 + hi) * 2048 + bc0);
    short8 bb1 = *(const short8*)(Wf1b + (size_t)(step * 2 + hi) * 2048 + bc1);
    acc[0][0] = __builtin_amdgcn_mfma_f32_32x32x16_bf16(a, ba0, acc[0][0], 0, 0, 0);
    acc[0][1] = __builtin_amdgcn_mfma_f32_32x32x16_bf16(a, ba1, acc[0][1], 0, 0, 0);
    acc[1][0] = __builtin_amdgcn_mfma_f32_32x32x16_bf16(a, bb0, acc[1][0], 0, 0, 0);
    acc[1][1] = __builtin_amdgcn_mfma_f32_32x32x16_bf16(a, bb1, acc[1][1], 0, 0, 0);
  }

  #pragma unroll
  for (int ct = 0; ct < 2; ct++) {
    int pcol = cb + ct * 32 + l31;
    #pragma unroll
    for (int reg = 0; reg < 16; reg++) {
      int row = (reg & 3) + 8 * (reg >> 2) + 4 * hi;
      int n = n0 + row;
      if (n < N) {
        P1f[(size_t)n * 256 + pcol] = f2bf(acc[0][ct][reg]);
        P2f[(size_t)n * 256 + pcol] = f2bf(acc[1][ct][reg]);
      }
    }
  }
}

// ---------------- fused edge encoder + Pe: Pe = (ef@We+be)@W1e + b1 (CSR-ordered) ----------------
__global__ __launch_bounds__(256, 4) void pe_fused(
    const float* __restrict__ ef, const int* __restrict__ elist,
    const short* __restrict__ Wfe, const float* __restrict__ b_edge,
    const short* __restrict__ Wf1e, const float* __restrict__ b1,
    short* __restrict__ Pe, int E)
{
  __shared__ short sE[64 * 24];
  __shared__ short sF[64 * 72];
  __shared__ int eid_s[64];

  int t = threadIdx.x;
  int ln = t & 63, w = t >> 6;
  int l31 = ln & 31, hi = ln >> 5;
  int e0 = blockIdx.x * 64;

  if (t < 64) eid_s[t] = (e0 + t < E) ? elist[e0 + t] : 0;
  __syncthreads();

  {
    int r = t >> 2, q = t & 3;
    float4 v = *(const float4*)(ef + (size_t)eid_s[r] * 16 + q * 4);
    short4v s;
    s[0] = f2bf(v.x); s[1] = f2bf(v.y); s[2] = f2bf(v.z); s[3] = f2bf(v.w);
    *(short4v*)(sE + r * 24 + q * 4) = s;
  }
  __syncthreads();

  {
    int rowb = (w & 1) * 32, cbq = (w >> 1) * 32;
    floatx16 acc;
    #pragma unroll
    for (int i = 0; i < 16; i++) acc[i] = 0.f;
    short8 a = *(const short8*)(sE + (rowb + l31) * 24 + hi * 8);
    short8 b = *(const short8*)(Wfe + (size_t)hi * 512 + (cbq + l31) * 8);
    acc = __builtin_amdgcn_mfma_f32_32x32x16_bf16(a, b, acc, 0, 0, 0);
    int col = cbq + l31;
    float bv = b_edge[col];
    #pragma unroll
    for (int reg = 0; reg < 16; reg++) {
      int row = rowb + (reg & 3) + 8 * (reg >> 2) + 4 * hi;
      sF[row * 72 + col] = f2bf(acc[reg] + bv);
    }
  }
  __syncthreads();

  const int cb = w * 64;
  const int bc0 = (cb + l31) * 8, bc1 = (cb + 32 + l31) * 8;
  floatx16 acc[2][2];
  #pragma unroll
  for (int rg = 0; rg < 2; rg++)
    #pragma unroll
    for (int ct = 0; ct < 2; ct++)
      #pragma unroll
      for (int i = 0; i < 16; i++) acc[rg][ct][i] = 0.f;

  #pragma unroll
  for (int step = 0; step < 4; step++) {
    short8 a0 = *(const short8*)(sF + l31 * 72 + step * 16 + hi * 8);
    short8 a1 = *(const short8*)(sF + (32 + l31) * 72 + step * 16 + hi * 8);
    short8 b0 = *(const short8*)(Wf1e + (size_t)(step * 2 + hi) * 2048 + bc0);
    short8 b1v = *(const short8*)(Wf1e + (size_t)(step * 2 + hi) * 2048 + bc1);
    acc[0][0] = __builtin_amdgcn_mfma_f32_32x32x16_bf16(a0, b0,  acc[0][0], 0, 0, 0);
    acc[0][1] = __builtin_amdgcn_mfma_f32_32x32x16_bf16(a0, b1v, acc[0][1], 0, 0, 0);
    acc[1][0] = __builtin_amdgcn_mfma_f32_32x32x16_bf16(a1, b0,  acc[1][0], 0, 0, 0);
    acc[1][1] = __builtin_amdgcn_mfma_f32_32x32x16_bf16(a1, b1v, acc[1][1], 0, 0, 0);
  }

  #pragma unroll
  for (int rg = 0; rg < 2; rg++)
    #pragma unroll
    for (int ct = 0; ct < 2; ct++) {
      int col = cb + ct * 32 + l31;
      float bv = b1[col];
      #pragma unroll
      for (int reg = 0; reg < 16; reg++) {
        int row = rg * 32 + (reg & 3) + 8 * (reg >> 2) + 4 * hi;
        Pe[(size_t)(e0 + row) * 256 + col] = f2bf(acc[rg][ct][reg] + bv);
      }
    }
}

// ---------------- message: relu(P1+P2+Pe) staging + GEMM2 + fused CSR agg ----------------
__global__ __launch_bounds__(256, 4) void msg_mfma(
    const short* __restrict__ P1f, const short* __restrict__ P2f,
    const short* __restrict__ Pe,
    const int* __restrict__ from_idx, const int* __restrict__ to_idx,
    const int* __restrict__ elist, const int* __restrict__ offsets,
    const short* __restrict__ Wf2, const float* __restrict__ b2,
    float* __restrict__ agg, int E)
{
  __shared__ short sA[64 * 264];
  __shared__ int from_s[64], to_s[64];
  __shared__ int rend_s[64], inter_s[64];

  int t = threadIdx.x;
  int ln = t & 63, w = t >> 6;
  int l31 = ln & 31, hi = ln >> 5;
  int cb = w * 64;
  int e0 = blockIdx.x * 64;

  if (t < 64) {
    int idx = e0 + t;
    int eid = (idx < E) ? elist[idx] : 0;
    from_s[t] = from_idx[eid];
    to_s[t] = (idx < E) ? to_idx[eid] : -1;
  }
  __syncthreads();

  if (t < 64) {
    int nd = to_s[t];
    bool head = (t == 0) || (nd != to_s[t - 1]);
    if (head && nd >= 0) {
      int re = t + 1;
      while (re < 64 && to_s[re] == nd) re++;
      rend_s[t] = re;
      inter_s[t] = (offsets[nd] == e0 + t) && (offsets[nd + 1] == e0 + re) ? 1 : 0;
    }
  }

  for (int i = t; i < 2048; i += 256) {
    int r = i >> 5, c8 = (i & 31) * 8;
    int nd = to_s[r]; if (nd < 0) nd = 0;
    short8 a = *(const short8*)(P1f + (size_t)from_s[r] * 256 + c8);
    short8 b = *(const short8*)(P2f + (size_t)nd * 256 + c8);
    short8 c = *(const short8*)(Pe + (size_t)(e0 + r) * 256 + c8);
    short8 o;
    #pragma unroll
    for (int j = 0; j < 8; j++)
      o[j] = f2bf(fmaxf(bf2f(a[j]) + bf2f(b[j]) + bf2f(c[j]), 0.f));
    *(short8*)(sA + r * 264 + c8) = o;
  }
  __syncthreads();

  const int arow0 = l31 * 264;
  const int arow1 = (32 + l31) * 264;
  const int bc0 = (cb + l31) * 8;
  const int bc1 = (cb + 32 + l31) * 8;

  floatx16 acc2[2][2];
  #pragma unroll
  for (int rg = 0; rg < 2; rg++)
    #pragma unroll
    for (int ct = 0; ct < 2; ct++)
      #pragma unroll
      for (int i = 0; i < 16; i++) acc2[rg][ct][i] = 0.f;

  {
    short8 b2buf[3][2];
    #pragma unroll
    for (int s = 0; s < 3; s++) {
      const short* bb = Wf2 + (size_t)(s * 2 + hi) * 2048;
      b2buf[s][0] = *(const short8*)(bb + bc0);
      b2buf[s][1] = *(const short8*)(bb + bc1);
    }
    short8 abuf[2][2];
    abuf[0][0] = *(const short8*)(sA + arow0 + hi * 8);
    abuf[0][1] = *(const short8*)(sA + arow1 + hi * 8);
    #pragma unroll
    for (int step = 0; step < 16; step++) {
      if (step + 1 < 16) {
        abuf[(step + 1) & 1][0] = *(const short8*)(sA + arow0 + (step + 1) * 16 + hi * 8);
        abuf[(step + 1) & 1][1] = *(const short8*)(sA + arow1 + (step + 1) * 16 + hi * 8);
      }
      acc2[0][0] = __builtin_amdgcn_mfma_f32_32x32x16_bf16(abuf[step & 1][0], b2buf[step % 3][0], acc2[0][0], 0, 0, 0);
      acc2[0][1] = __builtin_amdgcn_mfma_f32_32x32x16_bf16(abuf[step & 1][0], b2buf[step % 3][1], acc2[0][1], 0, 0, 0);
      acc2[1][0] = __builtin_amdgcn_mfma_f32_32x32x16_bf16(abuf[step & 1][1], b2buf[step % 3][0], acc2[1][0], 0, 0, 0);
      acc2[1][1] = __builtin_amdgcn_mfma_f32_32x32x16_bf16(abuf[step & 1][1], b2buf[step % 3][1], acc2[1][1], 0, 0, 0);
      if (step + 3 < 16) {
        const short* bb = Wf2 + (size_t)((step + 3) * 2 + hi) * 2048;
        b2buf[step % 3][0] = *(const short8*)(bb + bc0);
        b2buf[step % 3][1] = *(const short8*)(bb + bc1);
      }
    }
  }

  __syncthreads();
  #pragma unroll
  for (int rg = 0; rg < 2; rg++)
    #pragma unroll
    for (int ct = 0; ct < 2; ct++) {
      int col = cb + ct * 32 + l31;
      float bv = b2[col];
      #pragma unroll
      for (int reg = 0; reg < 16; reg++) {
        int row = rg * 32 + (reg & 3) + 8 * (reg >> 2) + 4 * hi;
        sA[row * 264 + col] = f2bf(acc2[rg][ct][reg] + bv);
      }
    }
  __syncthreads();

  {
    int c = t;
    for (int r = 0; r < 64; ) {
      int nd = to_s[r];
      if (nd < 0) break;
      int re = rend_s[r];
      float a = 0.f;
      for (int i = r; i < re; i++)
        a += bf2f(sA[i * 264 + c]);
      float* dst = agg + (size_t)nd * 256 + c;
      if (inter_s[r]) *dst = a;
      else unsafeAtomicAdd(dst, a);
      r = re;
    }
  }
}

// ---------------- node update + fused P1/P2; zeroes only boundary agg rows ----------------
__global__ __launch_bounds__(256, 3) void update_mfma_p(
    float* __restrict__ h, short* __restrict__ hbf, float* __restrict__ agg,
    const short* __restrict__ Wfu, const float* __restrict__ bu,
    const short* __restrict__ Wf1a, const short* __restrict__ Wf1b,
    short* __restrict__ P1f, short* __restrict__ P2f,
    const int* __restrict__ zflag, int want_p, int N)
{
  __shared__ short sA[32 * 392];
  __shared__ int zf_s[32];

  int t = threadIdx.x;
  int ln = t & 63, w = t >> 6;
  int l31 = ln & 31, hi = ln >> 5;
  int n0 = blockIdx.x * 32;

  if (t < 32) zf_s[t] = (n0 + t < N) ? zflag[n0 + t] : 0;

  for (int i = t; i < 512; i += 256) {
    int r = i >> 4, c = i & 15;
    short8 v = {0, 0, 0, 0, 0, 0, 0, 0};
    if (n0 + r < N) v = *(const short8*)(hbf + (size_t)(n0 + r) * 128 + c * 8);
    *(short8*)(sA + r * 392 + c * 8) = v;
  }
  for (int i = t; i < 2048; i += 256) {
    int r = i >> 6, c4 = i & 63;
    int2 pk = {0, 0};
    if (n0 + r < N) {
      float4 v = *(const float4*)(agg + (size_t)(n0 + r) * 256 + c4 * 4);
      pk.x = (int)(unsigned short)f2bf(v.x) | ((int)(unsigned short)f2bf(v.y) << 16);
      pk.y = (int)(unsigned short)f2bf(v.z) | ((int)(unsigned short)f2bf(v.w) << 16);
    }
    *(int2*)(sA + r * 392 + 128 + c4 * 4) = pk;
  }
  __syncthreads();

  {
    float4 z = {0.f, 0.f, 0.f, 0.f};
    for (int i = t; i < 2048; i += 256) {
      int r = i >> 6, c4 = i & 63;
      if (n0 + r < N && zf_s[r])
        *(float4*)(agg + (size_t)(n0 + r) * 256 + c4 * 4) = z;
    }
  }

  const int arow = l31 * 392;
  const int bcol = (w * 32 + l31) * 8;

  floatx16 acc;
  #pragma unroll
  for (int i = 0; i < 16; i++) acc[i] = 0.f;

  {
    short8 bbuf[3];
    #pragma unroll
    for (int s = 0; s < 3; s++)
      bbuf[s] = *(const short8*)(Wfu + (size_t)(s * 2 + hi) * 1024 + bcol);
    short8 abuf[2];
    abuf[0] = *(const short8*)(sA + arow + hi * 8);
    #pragma unroll
    for (int step = 0; step < 24; step++) {
      if (step + 1 < 24)
        abuf[(step + 1) & 1] = *(const short8*)(sA + arow + (step + 1) * 16 + hi * 8);
      acc = __builtin_amdgcn_mfma_f32_32x32x16_bf16(abuf[step & 1], bbuf[step % 3], acc, 0, 0, 0);
      if (step + 3 < 24)
        bbuf[step % 3] = *(const short8*)(Wfu + (size_t)((step + 3) * 2 + hi) * 1024 + bcol);
    }
  }

  __syncthreads();

  int col = w * 32 + l31;
  float bv = bu[col];
  #pragma unroll
  for (int reg = 0; reg < 16; reg++) {
    int row = (reg & 3) + 8 * (reg >> 2) + 4 * hi;
    int n = n0 + row;
    float nv = 0.f;
    if (n < N) nv = h[(size_t)n * 128 + col] + acc[reg] + bv;
    short bf = f2bf(nv);
    if (n < N) {
      h[(size_t)n * 128 + col] = nv;
      hbf[(size_t)n * 128 + col] = bf;
    }
    sA[row * 392 + col] = bf;
  }

  if (!want_p) return;
  __syncthreads();

  int cb = w * 64;
  const int bc0 = (cb + l31) * 8, bc1 = (cb + 32 + l31) * 8;
  floatx16 pacc[2][2];
  #pragma unroll
  for (int o = 0; o < 2; o++)
    #pragma unroll
    for (int ct = 0; ct < 2; ct++)
      #pragma unroll
      for (int i = 0; i < 16; i++) pacc[o][ct][i] = 0.f;

  #pragma unroll
  for (int step = 0; step < 8; step++) {
    short8 a = *(const short8*)(sA + arow + step * 16 + hi * 8);
    short8 ba0 = *(const short8*)(Wf1a + (size_t)(step * 2 + hi) * 2048 + bc0);
    short8 ba1 = *(const short8*)(Wf1a + (size_t)(step * 2 + hi) * 2048 + bc1);
    short8 bb0 = *(const short8*)(Wf1b + (size_t)(step * 2 + hi) * 2048 + bc0);
    short8 bb1 = *(const short8*)(Wf1b + (size_t)(step * 2 + hi) * 2048 + bc1);
    pacc[0][0] = __builtin_amdgcn_mfma_f32_32x32x16_bf16(a, ba0, pacc[0][0], 0, 0, 0);
    pacc[0][1] = __builtin_amdgcn_mfma_f32_32x32x16_bf16(a, ba1, pacc[0][1], 0, 0, 0);
    pacc[1][0] = __builtin_amdgcn_mfma_f32_32x32x16_bf16(a, bb0, pacc[1][0], 0, 0, 0);
    pacc[1][1] = __builtin_amdgcn_mfma_f32_32x32x16_bf16(a, bb1, pacc[1][1], 0, 0, 0);
  }

  #pragma unroll
  for (int ct = 0; ct < 2; ct++) {
    int pcol = cb + ct * 32 + l31;
    #pragma unroll
    for (int reg = 0; reg < 16; reg++) {
      int row = (reg & 3) + 8 * (reg >> 2) + 4 * hi;
      int n = n0 + row;
      if (n < N) {
        P1f[(size_t)n * 256 + pcol] = f2bf(pacc[0][ct][reg]);
        P2f[(size_t)n * 256 + pcol] = f2bf(pacc[1][ct][reg]);
      }
    }
  }
}

// ---------------- fused stack + attention features ----------------
__global__ __launch_bounds__(256, 3) void stack_attfeat(
    const float* __restrict__ h, const int* __restrict__ inv,
    const short* __restrict__ Wfa1, const float* __restrict__ ba1,
    const short* __restrict__ Wfa2, const float* __restrict__ ba2,
    const int* __restrict__ qsizes, const int* __restrict__ csizes,
    float* __restrict__ flat, short* __restrict__ flatT, short* __restrict__ tfb)
{
  __shared__ short sA[64 * 136];
  __shared__ int nd_s[64];

  int t = threadIdx.x;
  int ln = t & 63, w = t >> 6;
  int l31 = ln & 31, hi = ln >> 5;
  int r0 = blockIdx.x * 64;

  if (t < 64) nd_s[t] = inv[r0 + t];
  __syncthreads();

  for (int i = t; i < 1024; i += 256) {
    int r = i >> 4, c = (i & 15) * 8;
    int nd = nd_s[r];
    float4 v0 = {0.f, 0.f, 0.f, 0.f}, v1 = {0.f, 0.f, 0.f, 0.f};
    if (nd >= 0) {
      v0 = *(const float4*)(h + (size_t)nd * 128 + c);
      v1 = *(const float4*)(h + (size_t)nd * 128 + c + 4);
    }
    *(float4*)(flat + (size_t)(r0 + r) * 128 + c) = v0;
    *(float4*)(flat + (size_t)(r0 + r) * 128 + c + 4) = v1;
    short8 s;
    s[0] = f2bf(v0.x); s[1] = f2bf(v0.y); s[2] = f2bf(v0.z); s[3] = f2bf(v0.w);
    s[4] = f2bf(v1.x); s[5] = f2bf(v1.y); s[6] = f2bf(v1.z); s[7] = f2bf(v1.w);
    *(short8*)(sA + r * 136 + c) = s;
  }
  __syncthreads();

  for (int i = t; i < 8192; i += 256) {
    int d = i >> 6, r = i & 63;
    flatT[(size_t)blockIdx.x * 8192 + d * 64 + r] = sA[r * 136 + d];
  }

  const int arow0 = l31 * 136, arow1 = (32 + l31) * 136;
  const int bcol = (w * 32 + l31) * 8;
  int col = w * 32 + l31;

  floatx16 acc[2];
  #pragma unroll
  for (int rg = 0; rg < 2; rg++)
    #pragma unroll
    for (int i = 0; i < 16; i++) acc[rg][i] = 0.f;

  #pragma unroll
  for (int step = 0; step < 8; step++) {
    short8 a0 = *(const short8*)(sA + arow0 + step * 16 + hi * 8);
    short8 a1 = *(const short8*)(sA + arow1 + step * 16 + hi * 8);
    short8 bfr = *(const short8*)(Wfa1 + (size_t)(step * 2 + hi) * 1024 + bcol);
    acc[0] = __builtin_amdgcn_mfma_f32_32x32x16_bf16(a0, bfr, acc[0], 0, 0, 0);
    acc[1] = __builtin_amdgcn_mfma_f32_32x32x16_bf16(a1, bfr, acc[1], 0, 0, 0);
  }

  __syncthreads();
  {
    float bv = ba1[col];
    #pragma unroll
    for (int rg = 0; rg < 2; rg++)
      #pragma unroll
      for (int reg = 0; reg < 16; reg++) {
        int row = rg * 32 + (reg & 3) + 8 * (reg >> 2) + 4 * hi;
        sA[row * 136 + col] = f2bf(fmaxf(acc[rg][reg] + bv, 0.f));
      }
  }
  __syncthreads();

  floatx16 acc2[2];
  #pragma unroll
  for (int rg = 0; rg < 2; rg++)
    #pragma unroll
    for (int i = 0; i < 16; i++) acc2[rg][i] = 0.f;

  #pragma unroll
  for (int step = 0; step < 8; step++) {
    short8 a0 = *(const short8*)(sA + arow0 + step * 16 + hi * 8);
    short8 a1 = *(const short8*)(sA + arow1 + step * 16 + hi * 8);
    short8 bfr = *(const short8*)(Wfa2 + (size_t)(step * 2 + hi) * 1024 + bcol);
    acc2[0] = __builtin_amdgcn_mfma_f32_32x32x16_bf16(a0, bfr, acc2[0], 0, 0, 0);
    acc2[1] = __builtin_amdgcn_mfma_f32_32x32x16_bf16(a1, bfr, acc2[1], 0, 0, 0);
  }

  {
    float bv = ba2[col];
    #pragma unroll
    for (int rg = 0; rg < 2; rg++)
      #pragma unroll
      for (int reg = 0; reg < 16; reg++) {
        int row = r0 + rg * 32 + (reg & 3) + 8 * (reg >> 2) + 4 * hi;
        int part = row >> 14, b = (row >> 6) & 255, pp = row & 63;
        int sz = part ? csizes[b] : qsizes[b];
        float m = (pp < sz) ? 1.f : 0.f;
        tfb[(size_t)row * 128 + col] = f2bf((acc2[rg][reg] + bv) * m);
      }
  }
}

// ---------------- per-pair score: MFMA logits + MFMA PV ----------------
__global__ __launch_bounds__(256, 3) void score_kernel(
    const short* __restrict__ tfb, const float* __restrict__ flat,
    const short* __restrict__ flatT,
    const int* __restrict__ qsizes, const int* __restrict__ csizes,
    float* __restrict__ out)
{
  __shared__ float SL[64 * 65];
  __shared__ float SP2[64 * 65];
  __shared__ float red[8];

  int b = blockIdx.x, t = threadIdx.x;
  int ln = t & 63, w = t >> 6;
  int l31 = ln & 31, hi = ln >> 5;
  const short* tqb = tfb + (size_t)b * 8192;
  const short* tcb = tfb + (size_t)(256 + b) * 8192;
  const float* sq = flat + (size_t)b * 8192;
  const float* sc = flat + (size_t)(256 + b) * 8192;
  const short* sqT = flatT + (size_t)b * 8192;
  const short* scT = flatT + (size_t)(256 + b) * 8192;
  int qs = qsizes[b], cs = csizes[b];

  {
    int rowb = (w & 1) * 32, cbq = (w >> 1) * 32;
    floatx16 acc;
    #pragma unroll
    for (int i = 0; i < 16; i++) acc[i] = 0.f;
    #pragma unroll
    for (int step = 0; step < 8; step++) {
      short8 a  = *(const short8*)(tqb + (size_t)(rowb + l31) * 128 + step * 16 + hi * 8);
      short8 bf = *(const short8*)(tcb + (size_t)(cbq + l31) * 128 + step * 16 + hi * 8);
      acc = __builtin_amdgcn_mfma_f32_32x32x16_bf16(a, bf, acc, 0, 0, 0);
    }
    int ccol = cbq + l31;
    #pragma unroll
    for (int reg = 0; reg < 16; reg++) {
      int qrow = rowb + (reg & 3) + 8 * (reg >> 2) + 4 * hi;
      SL[qrow * 65 + ccol] = (qrow < qs && ccol < cs) ? acc[reg] * 10.0f : -1e9f;
    }
  }
  __syncthreads();

  float rmax = -1e30f, rsum = 0.f;
  if (t < 64) {
    int q = t;
    if (q < qs) {
      for (int c = 0; c < 64; c++) rmax = fmaxf(rmax, SL[q * 65 + c]);
      for (int c = 0; c < 64; c++) rsum += __expf(SL[q * 65 + c] - rmax);
    }
  } else if (t < 128) {
    int c = t - 64;
    if (c < cs) {
      float m = -1e30f;
      for (int q = 0; q < 64; q++) m = fmaxf(m, SL[q * 65 + c]);
      float s = 0.f;
      for (int q = 0; q < 64; q++) s += __expf(SL[q * 65 + c] - m);
      float inv = 1.0f / s;
      for (int q = 0; q < 64; q++) SP2[q * 65 + c] = __expf(SL[q * 65 + c] - m) * inv;
    } else {
      for (int q = 0; q < 64; q++) SP2[q * 65 + c] = 0.f;
    }
  }
  __syncthreads();

  if (t < 64) {
    int q = t;
    if (q < qs) {
      float inv = 1.0f / rsum;
      for (int c = 0; c < 64; c++) SL[q * 65 + c] = __expf(SL[q * 65 + c] - rmax) * inv;
    } else {
      for (int c = 0; c < 64; c++) SL[q * 65 + c] = 0.f;
    }
  }
  __syncthreads();

  int dcol = w * 32 + l31;
  floatx16 accq[2], accc[2];
  #pragma unroll
  for (int rt = 0; rt < 2; rt++) {
    #pragma unroll
    for (int i = 0; i < 16; i++) { accq[rt][i] = 0.f; accc[rt][i] = 0.f; }
  }

  #pragma unroll
  for (int rt = 0; rt < 2; rt++) {
    #pragma unroll
    for (int step = 0; step < 4; step++) {
      int kb = step * 16 + hi * 8;
      int row = rt * 32 + l31;
      short8 a;
      #pragma unroll
      for (int j = 0; j < 8; j++) a[j] = f2bf(SL[row * 65 + kb + j]);
      short8 bf = *(const short8*)(scT + (size_t)dcol * 64 + kb);
      accq[rt] = __builtin_amdgcn_mfma_f32_32x32x16_bf16(a, bf, accq[rt], 0, 0, 0);
    }
  }
  #pragma unroll
  for (int rt = 0; rt < 2; rt++) {
    #pragma unroll
    for (int step = 0; step < 4; step++) {
      int kb = step * 16 + hi * 8;
      int crow = rt * 32 + l31;
      short8 a;
      #pragma unroll
      for (int j = 0; j < 8; j++) a[j] = f2bf(SP2[(kb + j) * 65 + crow]);
      short8 bf = *(const short8*)(sqT + (size_t)dcol * 64 + kb);
      accc[rt] = __builtin_amdgcn_mfma_f32_32x32x16_bf16(a, bf, accc[rt], 0, 0, 0);
    }
  }

  float qpart = 0.f, cpart = 0.f;
  #pragma unroll
  for (int rt = 0; rt < 2; rt++) {
    #pragma unroll
    for (int reg = 0; reg < 16; reg++) {
      int row = rt * 32 + (reg & 3) + 8 * (reg >> 2) + 4 * hi;
      qpart += fmaxf(sq[(size_t)row * 128 + dcol] - accq[rt][reg], 0.f);
      cpart += fmaxf(sc[(size_t)row * 128 + dcol] - accc[rt][reg], 0.f);
    }
  }

  for (int off = 32; off > 0; off >>= 1) {
    qpart += __shfl_down(qpart, off);
    cpart += __shfl_down(cpart, off);
  }
  if ((t & 63) == 0) { red[w] = qpart; red[w + 4] = cpart; }
  __syncthreads();
  if (t == 0) {
    float qsum = red[0] + red[1] + red[2] + red[3];
    float csum = red[4] + red[5] + red[6] + red[7];
    out[b] = fminf(-qsum, -csum);
  }
}

// ---------------- launch ----------------
extern "C" void kernel_launch(void* const* d_in, const int* in_sizes, int n_in,
                              void* d_out, int out_size, void* d_ws, size_t ws_size,
                              hipStream_t stream)
{
  const float* nf  = (const float*)d_in[0];
  const float* ef  = (const float*)d_in[1];
  const int* from_idx = (const int*)d_in[2];
  const int* to_idx   = (const int*)d_in[3];
  const int* pos      = (const int*)d_in[4];
  const int* qsz      = (const int*)d_in[5];
  const int* csz      = (const int*)d_in[6];
  const float* W_node = (const float*)d_in[7];
  const float* b_node = (const float*)d_in[8];
  const float* W_edge = (const float*)d_in[9];
  const float* b_edge = (const float*)d_in[10];
  const float* W1 = (const float*)d_in[11];
  const float* b1 = (const float*)d_in[12];
  const float* W2 = (const float*)d_in[13];
  const float* b2 = (const float*)d_in[14];
  const float* Wu = (const float*)d_in[15];
  const float* bu = (const float*)d_in[16];
  const float* Wa1 = (const float*)d_in[17];
  const float* ba1 = (const float*)d_in[18];
  const float* Wa2 = (const float*)d_in[19];
  const float* ba2 = (const float*)d_in[20];
  float* out = (float*)d_out;

  int N = in_sizes[0] / NODE_F;
  int E = in_sizes[1] / EDGE_F;
  int Epad = (E + 63) & ~63;
  int PAD = 2 * B_PAIRS * MAXN;   // 32768
  int NB = (N + 1023) / 1024;     // scan blocks (<=64 for N<=65536)

  float* h    = (float*)d_ws;                              // N*128 f32
  float* agg  = h + (size_t)N * D;                         // N*256 f32
  short* hb   = (short*)(agg + (size_t)N * 256);           // N*128 bf16
  short* P1f  = hb + (size_t)N * D;                        // N*256 bf16
  short* P2f  = P1f + (size_t)N * 256;                     // N*256 bf16
  short* Wfn  = P2f + (size_t)N * 256;                     // 4096
  short* Wfe  = Wfn + 4096;                                // 1024
  short* Wf1a = Wfe + 1024;                                // 32768
  short* Wf1b = Wf1a + 32768;                              // 32768
  short* Wf1e = Wf1b + 32768;                              // 16384
  short* Wf2  = Wf1e + 16384;                              // 65536
  short* Wfu  = Wf2 + 65536;                               // 49152
  short* Wfa1 = Wfu + 49152;                               // 16384
  short* Wfa2 = Wfa1 + 16384;                              // 16384
  int*   deg     = (int*)(Wfa2 + 16384);                   // N
  int*   offsets = deg + N;                                // N+1
  int*   cursor  = offsets + N + 1;                        // N
  int*   elist   = cursor + N;                             // E
  int*   inv     = elist + E;                              // PAD
  int*   zflag   = inv + PAD;                              // N
  int*   partials = zflag + N;                             // NB (<=64)
  uintptr_t pb = ((uintptr_t)(partials + 64) + 15) & ~(uintptr_t)15;
  short* Pe = (short*)pb;                                  // Epad*256 bf16 (CSR order)
  float* flat  = (float*)Pe;                               // aliases Pe (post-loop)
  short* flatT = (short*)(flat + (size_t)PAD * D);
  short* tfb16 = flatT + (size_t)PAD * D;

  hipMemsetAsync(deg, 0, (size_t)N * sizeof(int), stream);
  init_kernel<<<916 + 256, 256, 0, stream>>>(
      W_node, W_edge, W1, W2, Wu, Wa1, Wa2,
      Wfn, Wfe, Wf1a, Wf1b, Wf1e, Wf2, Wfu, Wfa1, Wfa2,
      to_idx, deg, inv, E);
  scan1<<<NB, 1024, 0, stream>>>(deg, partials, N);
  scan2<<<1, 64, 0, stream>>>(partials, offsets, NB, N);
  scan3<<<NB, 1024, 0, stream>>>(deg, partials, offsets, cursor, zflag, pos, inv, N);
  scatter_csr<<<256, 256, 0, stream>>>(to_idx, cursor, elist, E);

  enc_nodes_p<<<(N + 31) / 32, 256, 0, stream>>>(nf, Wfn, b_node, h, hb,
                                                 Wf1a, Wf1b, P1f, P2f, N);
  pe_fused<<<Epad / 64, 256, 0, stream>>>(ef, elist, Wfe, b_edge, Wf1e, b1, Pe, E);

  hipMemsetAsync(agg, 0, (size_t)N * 256 * sizeof(float), stream);

  for (int s = 0; s < PROP_STEPS; s++) {
    msg_mfma<<<Epad / 64, 256, 0, stream>>>(P1f, P2f, Pe, from_idx, to_idx, elist, offsets,
                                            Wf2, b2, agg, E);
    update_mfma_p<<<(N + 31) / 32, 256, 0, stream>>>(h, hb, agg, Wfu, bu,
                                                     Wf1a, Wf1b, P1f, P2f, zflag,
                                                     (s + 1 < PROP_STEPS) ? 1 : 0, N);
  }

  stack_attfeat<<<PAD / 64, 256, 0, stream>>>(h, inv, Wfa1, ba1, Wfa2, ba2,
                                              qsz, csz, flat, flatT, tfb16);
  score_kernel<<<B_PAIRS, 256, 0, stream>>>(tfb16, flat, flatT, qsz, csz, out);
}